// Round 2
// baseline (2788.424 us; speedup 1.0000x reference)
//
#include <hip/hip_runtime.h>
#include <hip/hip_bf16.h>

// B=8, S=128, D=1024, H=4096, TOPK=256 -> k = 32768 per batch over S*H=524288 scores.
#define B_  8
#define S_  128
#define D_  1024
#define H_  4096
#define M_  (B_ * S_)          // 1024
#define NSCORE   (M_ * H_)     // 4,194,304
#define PERBATCH (S_ * H_)     // 524,288
#define TOPK_K   (256 * S_)    // 32,768
#define BAND_CAP 8192
#define MARGIN   4e-4f         // 2*eps; split-bf16 score error sigma ~5e-7, max ~3e-6 << eps

// ---------------- workspace layout (byte offsets) ----------------
#define G_OFF    0u            // g fp32 [1024,4096] 16MB; later hprev
#define SC_OFF   16777216u     // scores fp32 16MB; later hcurr
#define GHI_OFF  33554432u     // g_hi bf16 8MB
#define GLO_OFF  41943040u     // g_lo bf16 8MB
#define W2H_OFF  50331648u     // w2_hi bf16 32MB; after gemm2: wpb(8)+wcb(8)+xb(2)
#define W2L_OFF  83886080u     // w2_lo bf16 32MB; after gemm2: wdb(8)+act(8)
#define H1_OFF   117440512u    // hist1 2MB
#define H2_OFF   119537664u    // hist2 2MB
#define MISC_OFF 121634816u
#define SEL_OFF  MISC_OFF                 // 8x4096 u32 = 128KB
#define CNT_OFF  (MISC_OFF + 131072u)     // certainN[8] @ +0, bandN[8] @ +32
#define BIDX_OFF (MISC_OFF + 132096u)     // 8x8192 u32
#define BVAL_OFF (MISC_OFF + 394240u)     // 8x8192 f32
// value-path aliases (valid after gemm2_split has consumed w2 splits)
#define WPB_OFF  W2H_OFF
#define WCB_OFF  (W2H_OFF + 8388608u)
#define XB_OFF   (W2H_OFF + 16777216u)
#define WDB_OFF  W2L_OFF
#define ACT_OFF  (W2L_OFF + 8388608u)
// total ~116.7 MB

typedef __attribute__((ext_vector_type(8))) short short8;
typedef __attribute__((ext_vector_type(4))) float f32x4;

__device__ __forceinline__ unsigned tokey(float f) {
    unsigned u = __float_as_uint(f);
    return (u & 0x80000000u) ? ~u : (u | 0x80000000u);
}
__device__ __forceinline__ float keytofloat(unsigned k) {
    unsigned u = (k & 0x80000000u) ? (k & 0x7FFFFFFFu) : ~k;
    return __uint_as_float(u);
}
__device__ __forceinline__ unsigned short bfbits(float f) {
    __hip_bfloat16 h = __float2bfloat16(f);
    return *(unsigned short*)&h;
}

// ---------------- fp32 -> bf16 convert ----------------
__global__ __launch_bounds__(256) void f2bf_kernel(const float* __restrict__ in,
                                                   __hip_bfloat16* __restrict__ out, int n4) {
    int i = blockIdx.x * 256 + threadIdx.x;
    if (i >= n4) return;
    float4 v = *(const float4*)(in + (size_t)i * 4);
    out[(size_t)i*4+0] = __float2bfloat16(v.x);
    out[(size_t)i*4+1] = __float2bfloat16(v.y);
    out[(size_t)i*4+2] = __float2bfloat16(v.z);
    out[(size_t)i*4+3] = __float2bfloat16(v.w);
}

// ---------------- fp32 -> (hi, lo) bf16 split ----------------
__global__ __launch_bounds__(256) void split_kernel(const float* __restrict__ in,
                                                    unsigned short* __restrict__ hi,
                                                    unsigned short* __restrict__ lo, int n4) {
    int i = blockIdx.x * 256 + threadIdx.x;
    if (i >= n4) return;
    float4 v = *(const float4*)(in + (size_t)i * 4);
    unsigned short h0 = bfbits(v.x), h1 = bfbits(v.y), h2 = bfbits(v.z), h3 = bfbits(v.w);
    ushort4 hv = {h0, h1, h2, h3};
    float r0 = v.x - __bfloat162float(*(__hip_bfloat16*)&h0);
    float r1 = v.y - __bfloat162float(*(__hip_bfloat16*)&h1);
    float r2 = v.z - __bfloat162float(*(__hip_bfloat16*)&h2);
    float r3 = v.w - __bfloat162float(*(__hip_bfloat16*)&h3);
    ushort4 lv = {bfbits(r0), bfbits(r1), bfbits(r2), bfbits(r3)};
    *(ushort4*)(hi + (size_t)i*4) = hv;
    *(ushort4*)(lo + (size_t)i*4) = lv;
}

// ---------------- bias + relu + fp32 writeback + bf16 split (gate hidden) ----------------
__global__ __launch_bounds__(256) void g_post_kernel(float* __restrict__ g,
                                                     const float* __restrict__ b1,
                                                     unsigned short* __restrict__ hi,
                                                     unsigned short* __restrict__ lo) {
    int i = blockIdx.x * 256 + threadIdx.x;   // over 1M float4s
    if (i >= M_ * H_ / 4) return;
    int j = (i * 4) & (H_ - 1);
    float4 v = *(float4*)(g + (size_t)i * 4);
    v.x = fmaxf(v.x + b1[j+0], 0.0f);
    v.y = fmaxf(v.y + b1[j+1], 0.0f);
    v.z = fmaxf(v.z + b1[j+2], 0.0f);
    v.w = fmaxf(v.w + b1[j+3], 0.0f);
    *(float4*)(g + (size_t)i * 4) = v;
    unsigned short h0 = bfbits(v.x), h1 = bfbits(v.y), h2 = bfbits(v.z), h3 = bfbits(v.w);
    ushort4 hv = {h0, h1, h2, h3};
    float r0 = v.x - __bfloat162float(*(__hip_bfloat16*)&h0);
    float r1 = v.y - __bfloat162float(*(__hip_bfloat16*)&h1);
    float r2 = v.z - __bfloat162float(*(__hip_bfloat16*)&h2);
    float r3 = v.w - __bfloat162float(*(__hip_bfloat16*)&h3);
    ushort4 lv = {bfbits(r0), bfbits(r1), bfbits(r2), bfbits(r3)};
    *(ushort4*)(hi + (size_t)i*4) = hv;
    *(ushort4*)(lo + (size_t)i*4) = lv;
}

// ---------------- fp32 GEMM1 with split-K=4, atomic accumulate (no bias) ----------------
// A = x [1024,1024], B = gw1 [4096,1024] row-major (B^T operand), C = g [1024,4096].
__global__ __launch_bounds__(256) void sgemm1_atomic_kernel(const float* __restrict__ A,
                                                            const float* __restrict__ Bm,
                                                            float* __restrict__ C) {
    __shared__ float As[16][132];
    __shared__ float Bs[16][132];
    const int tid  = threadIdx.x;
    const int row0 = blockIdx.y * 128, col0 = blockIdx.x * 128;
    const int k0 = blockIdx.z * 256;
    const int ty = tid >> 4, tx = tid & 15;
    const int r_ld = tid >> 2;
    const int c_ld = (tid & 3) * 4;
    float acc[8][8] = {};
    for (int kt = k0; kt < k0 + 256; kt += 16) {
        #pragma unroll
        for (int half = 0; half < 2; half++) {
            int r = half * 64 + r_ld;
            float4 va = *(const float4*)(A  + (size_t)(row0 + r) * D_ + kt + c_ld);
            float4 vb = *(const float4*)(Bm + (size_t)(col0 + r) * D_ + kt + c_ld);
            As[c_ld+0][r] = va.x; As[c_ld+1][r] = va.y; As[c_ld+2][r] = va.z; As[c_ld+3][r] = va.w;
            Bs[c_ld+0][r] = vb.x; Bs[c_ld+1][r] = vb.y; Bs[c_ld+2][r] = vb.z; Bs[c_ld+3][r] = vb.w;
        }
        __syncthreads();
        #pragma unroll
        for (int k = 0; k < 16; k++) {
            float a[8], b[8];
            *(float4*)(a)   = *(const float4*)&As[k][ty*8];
            *(float4*)(a+4) = *(const float4*)&As[k][ty*8+4];
            *(float4*)(b)   = *(const float4*)&Bs[k][tx*8];
            *(float4*)(b+4) = *(const float4*)&Bs[k][tx*8+4];
            #pragma unroll
            for (int i = 0; i < 8; i++)
                #pragma unroll
                for (int j = 0; j < 8; j++)
                    acc[i][j] += a[i] * b[j];
        }
        __syncthreads();
    }
    #pragma unroll
    for (int i = 0; i < 8; i++) {
        int row = row0 + ty*8 + i;
        #pragma unroll
        for (int j = 0; j < 8; j++) {
            int col = col0 + tx*8 + j;
            unsafeAtomicAdd(&C[(size_t)row * H_ + col], acc[i][j]);
        }
    }
}

// ---------------- split-bf16 MFMA GEMM2: s = g.w2^T + b2 (3-term hi/lo) ----------------
// Tile 64x128 (MxN), BK=32, 256 thr, 4 waves each 64x32 (4x2 frags). Grid (32,16) = 512 blocks.
__global__ __launch_bounds__(256) void gemm2_split_kernel(const short* __restrict__ Ahg,
                                                          const short* __restrict__ Alg,
                                                          const short* __restrict__ Bhg,
                                                          const short* __restrict__ Blg,
                                                          const float* __restrict__ bias,
                                                          float* __restrict__ C) {
    __shared__ short Ah[64*32], Al[64*32], Bh[128*32], Bl[128*32];
    const int tid = threadIdx.x, lane = tid & 63, wave = tid >> 6;
    const int row0 = blockIdx.y * 64, col0 = blockIdx.x * 128;
    const int r_ld = tid >> 2;          // 0..63
    const int c_ld = (tid & 3) * 8;     // short offset 0,8,16,24
    f32x4 acc[4][2] = {};
    for (int kt = 0; kt < H_; kt += 32) {
        __builtin_amdgcn_global_load_lds(
            (const __attribute__((address_space(1))) unsigned*)(Ahg + (size_t)(row0 + r_ld) * H_ + kt + c_ld),
            (__attribute__((address_space(3))) unsigned*)(Ah + r_ld * 32 + c_ld), 16, 0, 0);
        __builtin_amdgcn_global_load_lds(
            (const __attribute__((address_space(1))) unsigned*)(Alg + (size_t)(row0 + r_ld) * H_ + kt + c_ld),
            (__attribute__((address_space(3))) unsigned*)(Al + r_ld * 32 + c_ld), 16, 0, 0);
        #pragma unroll
        for (int half = 0; half < 2; half++) {
            int r = half * 64 + r_ld;
            __builtin_amdgcn_global_load_lds(
                (const __attribute__((address_space(1))) unsigned*)(Bhg + (size_t)(col0 + r) * H_ + kt + c_ld),
                (__attribute__((address_space(3))) unsigned*)(Bh + r * 32 + c_ld), 16, 0, 0);
            __builtin_amdgcn_global_load_lds(
                (const __attribute__((address_space(1))) unsigned*)(Blg + (size_t)(col0 + r) * H_ + kt + c_ld),
                (__attribute__((address_space(3))) unsigned*)(Bl + r * 32 + c_ld), 16, 0, 0);
        }
        __syncthreads();
        short8 ah[4], al[4], bh[2], bl[2];
        #pragma unroll
        for (int i = 0; i < 4; i++) {
            ah[i] = *(const short8*)(Ah + (i*16 + (lane & 15)) * 32 + (lane >> 4) * 8);
            al[i] = *(const short8*)(Al + (i*16 + (lane & 15)) * 32 + (lane >> 4) * 8);
        }
        #pragma unroll
        for (int j = 0; j < 2; j++) {
            bh[j] = *(const short8*)(Bh + (wave*32 + j*16 + (lane & 15)) * 32 + (lane >> 4) * 8);
            bl[j] = *(const short8*)(Bl + (wave*32 + j*16 + (lane & 15)) * 32 + (lane >> 4) * 8);
        }
        #pragma unroll
        for (int i = 0; i < 4; i++)
            #pragma unroll
            for (int j = 0; j < 2; j++) {
                acc[i][j] = __builtin_amdgcn_mfma_f32_16x16x32_bf16(al[i], bh[j], acc[i][j], 0, 0, 0);
                acc[i][j] = __builtin_amdgcn_mfma_f32_16x16x32_bf16(ah[i], bl[j], acc[i][j], 0, 0, 0);
                acc[i][j] = __builtin_amdgcn_mfma_f32_16x16x32_bf16(ah[i], bh[j], acc[i][j], 0, 0, 0);
            }
        __syncthreads();
    }
    #pragma unroll
    for (int i = 0; i < 4; i++) {
        int row = row0 + i*16 + (lane >> 4) * 4;
        #pragma unroll
        for (int j = 0; j < 2; j++) {
            int col = col0 + wave*32 + j*16 + (lane & 15);
            float bv = bias[col];
            #pragma unroll
            for (int r = 0; r < 4; r++)
                C[(size_t)(row + r) * H_ + col] = acc[i][j][r] + bv;
        }
    }
}

// ---------------- bf16 MFMA GEMM (value path, unchanged from R1) ----------------
__global__ __launch_bounds__(256) void bgemm_bt_kernel(const short* __restrict__ A,
                                                       const short* __restrict__ B0,
                                                       const short* __restrict__ B1,
                                                       float* __restrict__ C0,
                                                       float* __restrict__ C1,
                                                       const float* __restrict__ bias,
                                                       int N, int K) {
    const short* Bw = (blockIdx.z == 0) ? B0 : B1;
    float*       C  = (blockIdx.z == 0) ? C0 : C1;
    __shared__ short As[128 * 32];
    __shared__ short Bs[128 * 32];
    const int tid  = threadIdx.x;
    const int lane = tid & 63;
    const int wave = tid >> 6;
    const int wr = wave >> 1, wc = wave & 1;
    const int row0 = blockIdx.y * 128, col0 = blockIdx.x * 128;
    const int r_ld = tid >> 2;
    const int c_ld = (tid & 3) * 8;
    f32x4 acc[4][4] = {};
    for (int kt = 0; kt < K; kt += 32) {
        #pragma unroll
        for (int half = 0; half < 2; half++) {
            int r = half * 64 + r_ld;
            __builtin_amdgcn_global_load_lds(
                (const __attribute__((address_space(1))) unsigned*)(A + (size_t)(row0 + r) * K + kt + c_ld),
                (__attribute__((address_space(3))) unsigned*)(As + r * 32 + c_ld), 16, 0, 0);
            __builtin_amdgcn_global_load_lds(
                (const __attribute__((address_space(1))) unsigned*)(Bw + (size_t)(col0 + r) * K + kt + c_ld),
                (__attribute__((address_space(3))) unsigned*)(Bs + r * 32 + c_ld), 16, 0, 0);
        }
        __syncthreads();
        short8 af[4], bfr[4];
        #pragma unroll
        for (int t = 0; t < 4; t++) {
            af[t]  = *(const short8*)(As + (wr*64 + t*16 + (lane & 15)) * 32 + (lane >> 4) * 8);
            bfr[t] = *(const short8*)(Bs + (wc*64 + t*16 + (lane & 15)) * 32 + (lane >> 4) * 8);
        }
        #pragma unroll
        for (int tm = 0; tm < 4; tm++)
            #pragma unroll
            for (int tn = 0; tn < 4; tn++)
                acc[tm][tn] = __builtin_amdgcn_mfma_f32_16x16x32_bf16(af[tm], bfr[tn], acc[tm][tn], 0, 0, 0);
        __syncthreads();
    }
    #pragma unroll
    for (int tm = 0; tm < 4; tm++) {
        int row = row0 + wr*64 + tm*16 + (lane >> 4) * 4;
        #pragma unroll
        for (int tn = 0; tn < 4; tn++) {
            int col = col0 + wc*64 + tn*16 + (lane & 15);
            float bv = bias ? bias[col] : 0.0f;
            #pragma unroll
            for (int r = 0; r < 4; r++)
                C[(size_t)(row + r) * N + col] = acc[tm][tn][r] + bv;
        }
    }
}

// ---------------- top-k radix select (on approximate scores) ----------------
__global__ __launch_bounds__(256) void hist1_kernel(const float* __restrict__ scores,
                                                    unsigned* __restrict__ hist) {
    int i = blockIdx.x * 256 + threadIdx.x;
    if (i >= NSCORE) return;
    int b = i >> 19;
    unsigned key = tokey(scores[i]);
    atomicAdd(&hist[(b << 16) + (key >> 16)], 1u);
}

__global__ __launch_bounds__(256) void hist2_kernel(const float* __restrict__ scores,
                                                    const unsigned* __restrict__ P1,
                                                    unsigned* __restrict__ hist2) {
    int i = blockIdx.x * 256 + threadIdx.x;
    if (i >= NSCORE) return;
    int b = i >> 19;
    unsigned key = tokey(scores[i]);
    if ((key >> 16) == P1[b]) atomicAdd(&hist2[(b << 16) + (key & 0xFFFFu)], 1u);
}

__global__ __launch_bounds__(256) void scan_hist_kernel(const unsigned* __restrict__ hist,
                                                        const unsigned* __restrict__ kin,
                                                        unsigned* __restrict__ binOut,
                                                        unsigned* __restrict__ kOut,
                                                        unsigned kconst) {
    int b = blockIdx.x, tid = threadIdx.x;
    const unsigned* h = hist + ((size_t)b << 16);
    unsigned k = kin ? kin[b] : kconst;
    __shared__ unsigned S[256];
    __shared__ int tstar;
    unsigned s = 0;
    const unsigned* seg = h + tid * 256;
    for (int i = 0; i < 256; i++) s += seg[i];
    S[tid] = s;
    __syncthreads();
    for (int off = 1; off < 256; off <<= 1) {
        unsigned a = S[tid];
        unsigned v = (tid + off < 256) ? S[tid + off] : 0u;
        __syncthreads();
        S[tid] = a + v;
        __syncthreads();
    }
    unsigned St = S[tid];
    unsigned Sn = (tid < 255) ? S[tid + 1] : 0u;
    if (St >= k && (tid == 255 || Sn < k)) tstar = tid;
    __syncthreads();
    if (tid == 0) {
        int t = tstar;
        unsigned runn = (t < 255) ? S[t + 1] : 0u;
        unsigned bin = (unsigned)t * 256u, kprime = 1u;
        for (int i = 255; i >= 0; i--) {
            unsigned c = h[t * 256 + i];
            if (runn + c >= k) { bin = (unsigned)(t * 256 + i); kprime = k - runn; break; }
            runn += c;
        }
        binOut[b] = bin;
        kOut[b]  = kprime;
    }
}

// ---------------- classify: certain-in marks, band append ----------------
__global__ __launch_bounds__(256) void classify_kernel(const float* __restrict__ scores,
                                                       const unsigned* __restrict__ B1,
                                                       const unsigned* __restrict__ B2,
                                                       unsigned* __restrict__ sel,
                                                       unsigned* __restrict__ certainN,
                                                       unsigned* __restrict__ bandN,
                                                       unsigned* __restrict__ bandIdx) {
    int i = blockIdx.x * 256 + threadIdx.x;
    if (i >= NSCORE) return;
    int b = i >> 19;                  // wave-uniform (524288 % 64 == 0)
    float sv = scores[i];
    float Tf = keytofloat((B1[b] << 16) | B2[b]);
    bool certain = sv > Tf + MARGIN;
    unsigned long long m = __ballot(certain);
    if (certain) sel[(b << 12) + (i & (H_ - 1))] = 1u;
    else if (sv >= Tf - MARGIN) {
        unsigned slot = atomicAdd(&bandN[b], 1u);
        if (slot < BAND_CAP) bandIdx[(b << 13) + slot] = (unsigned)(i & (PERBATCH - 1));
    }
    if ((threadIdx.x & 63) == 0 && m) atomicAdd(&certainN[b], (unsigned)__popcll(m));
}

// ---------------- exact fp32 score for band entries (one wave each) ----------------
__global__ __launch_bounds__(256) void band_exact_kernel(const float* __restrict__ g,
                                                         const float* __restrict__ w2,
                                                         const float* __restrict__ b2,
                                                         const unsigned* __restrict__ bandN,
                                                         const unsigned* __restrict__ bandIdx,
                                                         float* __restrict__ bandVal) {
    int wid = (blockIdx.x * 256 + threadIdx.x) >> 6;   // 0..1023 (grid = 256 blocks)
    int lane = threadIdx.x & 63;
    for (int b = 0; b < B_; b++) {
        int n = bandN[b]; if (n > BAND_CAP) n = BAND_CAP;
        for (int j = wid; j < n; j += 1024) {
            unsigned f = bandIdx[(b << 13) + j];
            int m = b * S_ + (int)(f >> 12);
            int h = (int)(f & (H_ - 1));
            const float* gr = g  + (size_t)m * H_;
            const float* wr = w2 + (size_t)h * H_;
            float s = 0.0f;
            for (int c = lane * 4; c < H_; c += 256) {
                float4 a = *(const float4*)(gr + c);
                float4 w = *(const float4*)(wr + c);
                s += a.x*w.x + a.y*w.y + a.z*w.z + a.w*w.w;
            }
            #pragma unroll
            for (int off = 32; off; off >>= 1) s += __shfl_xor(s, off);
            if (lane == 0) bandVal[(b << 13) + j] = s + b2[h];
        }
    }
}

// ---------------- select top-r of band by (exact desc, flat idx asc) ----------------
__global__ __launch_bounds__(256) void band_select_kernel(const float* __restrict__ bandVal,
                                                          const unsigned* __restrict__ bandIdx,
                                                          const unsigned* __restrict__ bandN,
                                                          const unsigned* __restrict__ certainN,
                                                          unsigned* __restrict__ sel) {
    __shared__ float  sv[BAND_CAP];
    __shared__ unsigned si[BAND_CAP];
    int b = blockIdx.x, tid = threadIdx.x;
    int n = bandN[b]; if (n > BAND_CAP) n = BAND_CAP;
    int r = TOPK_K - (int)certainN[b];
    if (r <= 0) return;
    if (r >= n) {
        for (int j = tid; j < n; j += 256)
            sel[(b << 12) + (bandIdx[(b << 13) + j] & (H_ - 1))] = 1u;
        return;
    }
    for (int j = tid; j < n; j += 256) {
        sv[j] = bandVal[(b << 13) + j];
        si[j] = bandIdx[(b << 13) + j];
    }
    __syncthreads();
    for (int j = tid; j < n; j += 256) {
        float vj = sv[j]; unsigned fj = si[j];
        int rank = 0;
        for (int l = 0; l < n; l++) {
            float vl = sv[l]; unsigned fl = si[l];
            rank += (vl > vj) || (vl == vj && fl < fj);
        }
        if (rank < r) sel[(b << 12) + (fj & (H_ - 1))] = 1u;
    }
}

// ---------------- select + bias + exact GELU -> bf16 ----------------
__global__ __launch_bounds__(256) void act_kernel(const float* __restrict__ hprev,
                                                  const float* __restrict__ hcurr,
                                                  const float* __restrict__ bprev,
                                                  const float* __restrict__ bcurr,
                                                  const unsigned* __restrict__ sel,
                                                  __hip_bfloat16* __restrict__ act) {
    int i = blockIdx.x * 256 + threadIdx.x;
    if (i >= NSCORE) return;
    int h = i & (H_ - 1);
    int b = i >> 19;
    float v = sel[(b << 12) + h] ? (hprev[i] + bprev[h]) : (hcurr[i] + bcurr[h]);
    float gl = 0.5f * v * (1.0f + erff(v * 0.70710678118654752440f));
    act[i] = __float2bfloat16(gl);
}

extern "C" void kernel_launch(void* const* d_in, const int* in_sizes, int n_in,
                              void* d_out, int out_size, void* d_ws, size_t ws_size,
                              hipStream_t stream) {
    const float* x     = (const float*)d_in[0];
    const float* wprev = (const float*)d_in[1];
    const float* bprev = (const float*)d_in[2];
    const float* wcurr = (const float*)d_in[3];
    const float* bcurr = (const float*)d_in[4];
    const float* gw1   = (const float*)d_in[5];
    const float* gb1   = (const float*)d_in[6];
    const float* gw2   = (const float*)d_in[7];
    const float* gb2   = (const float*)d_in[8];
    const float* dw    = (const float*)d_in[9];
    const float* db    = (const float*)d_in[10];
    float* out = (float*)d_out;
    char* ws = (char*)d_ws;

    float* g      = (float*)(ws + G_OFF);
    float* scores = (float*)(ws + SC_OFF);
    float* hprev  = (float*)(ws + G_OFF);
    float* hcurr  = (float*)(ws + SC_OFF);
    unsigned short* ghi = (unsigned short*)(ws + GHI_OFF);
    unsigned short* glo = (unsigned short*)(ws + GLO_OFF);
    unsigned short* w2h = (unsigned short*)(ws + W2H_OFF);
    unsigned short* w2l = (unsigned short*)(ws + W2L_OFF);
    __hip_bfloat16* xb  = (__hip_bfloat16*)(ws + XB_OFF);
    __hip_bfloat16* wpb = (__hip_bfloat16*)(ws + WPB_OFF);
    __hip_bfloat16* wcb = (__hip_bfloat16*)(ws + WCB_OFF);
    __hip_bfloat16* wdb = (__hip_bfloat16*)(ws + WDB_OFF);
    __hip_bfloat16* act = (__hip_bfloat16*)(ws + ACT_OFF);
    unsigned* hist1   = (unsigned*)(ws + H1_OFF);
    unsigned* hist2   = (unsigned*)(ws + H2_OFF);
    unsigned* sel     = (unsigned*)(ws + SEL_OFF);
    unsigned* certN   = (unsigned*)(ws + CNT_OFF);
    unsigned* bandN   = (unsigned*)(ws + CNT_OFF + 32);
    unsigned* bandIdx = (unsigned*)(ws + BIDX_OFF);
    float*    bandVal = (float*)(ws + BVAL_OFF);
    unsigned* B1c = (unsigned*)(ws + CNT_OFF + 64);
    unsigned* K1c = (unsigned*)(ws + CNT_OFF + 96);
    unsigned* B2c = (unsigned*)(ws + CNT_OFF + 128);
    unsigned* K2c = (unsigned*)(ws + CNT_OFF + 160);

    // zero: g (atomic accum), hists, sel+counters
    hipMemsetAsync(ws + G_OFF, 0, 16777216, stream);
    hipMemsetAsync(ws + H1_OFF, 0, 4194304, stream);            // hist1+hist2 contiguous
    hipMemsetAsync(ws + SEL_OFF, 0, 131072 + 256, stream);      // sel + counters

    // gate GEMM1 (fp32, split-K=4, atomics) then bias+relu+split
    sgemm1_atomic_kernel<<<dim3(H_/128, M_/128, 4), 256, 0, stream>>>(x, gw1, g);
    g_post_kernel<<<(M_*H_/4 + 255)/256, 256, 0, stream>>>(g, gb1, ghi, glo);

    // split w2, then split-bf16 MFMA GEMM2
    split_kernel<<<(H_*H_/4 + 255)/256, 256, 0, stream>>>(gw2, w2h, w2l, H_*H_/4);
    gemm2_split_kernel<<<dim3(H_/128, M_/64), 256, 0, stream>>>(
        (const short*)ghi, (const short*)glo, (const short*)w2h, (const short*)w2l, gb2, scores);

    // value-path bf16 copies (alias w2 split regions -> must follow gemm2)
    f2bf_kernel<<<(M_*D_/4 + 255)/256, 256, 0, stream>>>(x,     xb,  M_*D_/4);
    f2bf_kernel<<<(H_*D_/4 + 255)/256, 256, 0, stream>>>(wprev, wpb, H_*D_/4);
    f2bf_kernel<<<(H_*D_/4 + 255)/256, 256, 0, stream>>>(wcurr, wcb, H_*D_/4);
    f2bf_kernel<<<(H_*D_/4 + 255)/256, 256, 0, stream>>>(dw,    wdb, H_*D_/4);

    // radix threshold on approximate scores
    hist1_kernel<<<NSCORE/256, 256, 0, stream>>>(scores, hist1);
    scan_hist_kernel<<<B_, 256, 0, stream>>>(hist1, nullptr, B1c, K1c, TOPK_K);
    hist2_kernel<<<NSCORE/256, 256, 0, stream>>>(scores, B1c, hist2);
    scan_hist_kernel<<<B_, 256, 0, stream>>>(hist2, K1c, B2c, K2c, 0u);

    // certain marks + band; exact recompute; band top-r
    classify_kernel<<<NSCORE/256, 256, 0, stream>>>(scores, B1c, B2c, sel, certN, bandN, bandIdx);
    band_exact_kernel<<<256, 256, 0, stream>>>(g, gw2, gb2, bandN, bandIdx, bandVal);
    band_select_kernel<<<B_, 256, 0, stream>>>(bandVal, bandIdx, bandN, certN, sel);

    // value path
    bgemm_bt_kernel<<<dim3(H_/128, M_/128, 2), 256, 0, stream>>>(
        (const short*)xb, (const short*)wpb, (const short*)wcb, hprev, hcurr, nullptr, H_, D_);
    act_kernel<<<NSCORE/256, 256, 0, stream>>>(hprev, hcurr, bprev, bcurr, sel, act);
    bgemm_bt_kernel<<<dim3(D_/128, M_/128, 1), 256, 0, stream>>>(
        (const short*)act, (const short*)wdb, (const short*)wdb, out, out, db, D_, H_);
}

// Round 3
// 1050.651 us; speedup vs baseline: 2.6540x; 2.6540x over previous
//
#include <hip/hip_runtime.h>
#include <hip/hip_bf16.h>

// B=8, S=128, D=1024, H=4096, TOPK=256 -> k = 32768 per batch over S*H=524288 scores.
#define B_  8
#define S_  128
#define D_  1024
#define H_  4096
#define M_  (B_ * S_)          // 1024
#define NSCORE   (M_ * H_)     // 4,194,304
#define PERBATCH (S_ * H_)     // 524,288
#define TOPK_K   (256 * S_)    // 32,768
#define BAND_CAP 8192
#define MARGIN   4e-4f         // split-bf16 score error sigma ~5e-7, max ~3e-6 << MARGIN

// ---------------- workspace layout (byte offsets) ----------------
#define G_OFF    0u            // gemm1 partial0 / g fp32 [1024,4096] 16MB; later hprev
#define SC_OFF   16777216u     // scores fp32 16MB; later hcurr
#define GHI_OFF  33554432u     // g_hi bf16 8MB
#define GLO_OFF  41943040u     // g_lo bf16 8MB
#define W2H_OFF  50331648u     // gemm1 partial1 (16MB), then w2_hi bf16 32MB; after gemm2: wpb+wcb+xb
#define W2L_OFF  83886080u     // w2_lo bf16 32MB; after gemm2: wdb(8)+act(8)
#define H1_OFF   117440512u    // hist1 2MB
#define H2_OFF   119537664u    // hist2 2MB
#define MISC_OFF 121634816u
#define SEL_OFF  MISC_OFF                 // 8x4096 u32 = 128KB
#define CNT_OFF  (MISC_OFF + 131072u)     // certainN[8] @ +0, bandN[8] @ +32, B1/K1/B2/K2 @ +64..
#define PART_OFF (MISC_OFF + 131584u)     // per-block certain counts: 1024 u32 (4KB)
#define BIDX_OFF (MISC_OFF + 135680u)     // 8x8192 u32
#define BVAL_OFF (MISC_OFF + 397824u)     // 8x8192 f32
// value-path aliases (valid after gemm2_split has consumed w2 splits)
#define WPB_OFF  W2H_OFF
#define WCB_OFF  (W2H_OFF + 8388608u)
#define XB_OFF   (W2H_OFF + 16777216u)
#define WDB_OFF  W2L_OFF
#define ACT_OFF  (W2L_OFF + 8388608u)
// total ~122.3 MB (same footprint as R2)

typedef __attribute__((ext_vector_type(8))) short short8;
typedef __attribute__((ext_vector_type(4))) float f32x4;

__device__ __forceinline__ unsigned tokey(float f) {
    unsigned u = __float_as_uint(f);
    return (u & 0x80000000u) ? ~u : (u | 0x80000000u);
}
__device__ __forceinline__ float keytofloat(unsigned k) {
    unsigned u = (k & 0x80000000u) ? (k & 0x7FFFFFFFu) : ~k;
    return __uint_as_float(u);
}
__device__ __forceinline__ unsigned short bfbits(float f) {
    __hip_bfloat16 h = __float2bfloat16(f);
    return *(unsigned short*)&h;
}

// ---------------- fp32 -> bf16 convert ----------------
__global__ __launch_bounds__(256) void f2bf_kernel(const float* __restrict__ in,
                                                   __hip_bfloat16* __restrict__ out, int n4) {
    int i = blockIdx.x * 256 + threadIdx.x;
    if (i >= n4) return;
    float4 v = *(const float4*)(in + (size_t)i * 4);
    out[(size_t)i*4+0] = __float2bfloat16(v.x);
    out[(size_t)i*4+1] = __float2bfloat16(v.y);
    out[(size_t)i*4+2] = __float2bfloat16(v.z);
    out[(size_t)i*4+3] = __float2bfloat16(v.w);
}

// ---------------- fp32 -> (hi, lo) bf16 split ----------------
__global__ __launch_bounds__(256) void split_kernel(const float* __restrict__ in,
                                                    unsigned short* __restrict__ hi,
                                                    unsigned short* __restrict__ lo, int n4) {
    int i = blockIdx.x * 256 + threadIdx.x;
    if (i >= n4) return;
    float4 v = *(const float4*)(in + (size_t)i * 4);
    unsigned short h0 = bfbits(v.x), h1 = bfbits(v.y), h2 = bfbits(v.z), h3 = bfbits(v.w);
    ushort4 hv = {h0, h1, h2, h3};
    float r0 = v.x - __bfloat162float(*(__hip_bfloat16*)&h0);
    float r1 = v.y - __bfloat162float(*(__hip_bfloat16*)&h1);
    float r2 = v.z - __bfloat162float(*(__hip_bfloat16*)&h2);
    float r3 = v.w - __bfloat162float(*(__hip_bfloat16*)&h3);
    ushort4 lv = {bfbits(r0), bfbits(r1), bfbits(r2), bfbits(r3)};
    *(ushort4*)(hi + (size_t)i*4) = hv;
    *(ushort4*)(lo + (size_t)i*4) = lv;
}

// ---------------- sum split-K partials + bias + relu + fp32 writeback + bf16 split ----------------
__global__ __launch_bounds__(256) void g_post_kernel(float* __restrict__ p0,
                                                     const float* __restrict__ p1,
                                                     const float* __restrict__ b1,
                                                     unsigned short* __restrict__ hi,
                                                     unsigned short* __restrict__ lo) {
    int i = blockIdx.x * 256 + threadIdx.x;   // over 1M float4s
    if (i >= M_ * H_ / 4) return;
    int j = (i * 4) & (H_ - 1);
    float4 v = *(float4*)(p0 + (size_t)i * 4);
    float4 w = *(const float4*)(p1 + (size_t)i * 4);
    v.x = fmaxf(v.x + w.x + b1[j+0], 0.0f);
    v.y = fmaxf(v.y + w.y + b1[j+1], 0.0f);
    v.z = fmaxf(v.z + w.z + b1[j+2], 0.0f);
    v.w = fmaxf(v.w + w.w + b1[j+3], 0.0f);
    *(float4*)(p0 + (size_t)i * 4) = v;
    unsigned short h0 = bfbits(v.x), h1 = bfbits(v.y), h2 = bfbits(v.z), h3 = bfbits(v.w);
    ushort4 hv = {h0, h1, h2, h3};
    float r0 = v.x - __bfloat162float(*(__hip_bfloat16*)&h0);
    float r1 = v.y - __bfloat162float(*(__hip_bfloat16*)&h1);
    float r2 = v.z - __bfloat162float(*(__hip_bfloat16*)&h2);
    float r3 = v.w - __bfloat162float(*(__hip_bfloat16*)&h3);
    ushort4 lv = {bfbits(r0), bfbits(r1), bfbits(r2), bfbits(r3)};
    *(ushort4*)(hi + (size_t)i*4) = hv;
    *(ushort4*)(lo + (size_t)i*4) = lv;
}

// ---------------- fp32 GEMM1, split-K=2 into separate buffers (no atomics) ----------------
// A = x [1024,1024], B = gw1 [4096,1024] row-major (B^T operand). blockIdx.z picks K-half.
__global__ __launch_bounds__(256) void sgemm1_kernel(const float* __restrict__ A,
                                                     const float* __restrict__ Bm,
                                                     float* __restrict__ P0,
                                                     float* __restrict__ P1) {
    __shared__ float As[16][132];
    __shared__ float Bs[16][132];
    float* C = blockIdx.z ? P1 : P0;
    const int k0 = blockIdx.z * (D_ / 2);
    const int tid  = threadIdx.x;
    const int row0 = blockIdx.y * 128, col0 = blockIdx.x * 128;
    const int ty = tid >> 4, tx = tid & 15;
    const int r_ld = tid >> 2;
    const int c_ld = (tid & 3) * 4;
    float acc[8][8] = {};
    for (int kt = k0; kt < k0 + D_ / 2; kt += 16) {
        #pragma unroll
        for (int half = 0; half < 2; half++) {
            int r = half * 64 + r_ld;
            float4 va = *(const float4*)(A  + (size_t)(row0 + r) * D_ + kt + c_ld);
            float4 vb = *(const float4*)(Bm + (size_t)(col0 + r) * D_ + kt + c_ld);
            As[c_ld+0][r] = va.x; As[c_ld+1][r] = va.y; As[c_ld+2][r] = va.z; As[c_ld+3][r] = va.w;
            Bs[c_ld+0][r] = vb.x; Bs[c_ld+1][r] = vb.y; Bs[c_ld+2][r] = vb.z; Bs[c_ld+3][r] = vb.w;
        }
        __syncthreads();
        #pragma unroll
        for (int k = 0; k < 16; k++) {
            float a[8], b[8];
            *(float4*)(a)   = *(const float4*)&As[k][ty*8];
            *(float4*)(a+4) = *(const float4*)&As[k][ty*8+4];
            *(float4*)(b)   = *(const float4*)&Bs[k][tx*8];
            *(float4*)(b+4) = *(const float4*)&Bs[k][tx*8+4];
            #pragma unroll
            for (int i = 0; i < 8; i++)
                #pragma unroll
                for (int j = 0; j < 8; j++)
                    acc[i][j] += a[i] * b[j];
        }
        __syncthreads();
    }
    #pragma unroll
    for (int i = 0; i < 8; i++) {
        int row = row0 + ty*8 + i;
        #pragma unroll
        for (int j = 0; j < 8; j++)
            C[(size_t)row * H_ + col0 + tx*8 + j] = acc[i][j];
    }
}

// ---------------- split-bf16 MFMA GEMM2: s = g.w2^T + b2 (3-term hi/lo) ----------------
__global__ __launch_bounds__(256) void gemm2_split_kernel(const short* __restrict__ Ahg,
                                                          const short* __restrict__ Alg,
                                                          const short* __restrict__ Bhg,
                                                          const short* __restrict__ Blg,
                                                          const float* __restrict__ bias,
                                                          float* __restrict__ C) {
    __shared__ short Ah[64*32], Al[64*32], Bh[128*32], Bl[128*32];
    const int tid = threadIdx.x, lane = tid & 63, wave = tid >> 6;
    const int row0 = blockIdx.y * 64, col0 = blockIdx.x * 128;
    const int r_ld = tid >> 2;
    const int c_ld = (tid & 3) * 8;
    f32x4 acc[4][2] = {};
    for (int kt = 0; kt < H_; kt += 32) {
        __builtin_amdgcn_global_load_lds(
            (const __attribute__((address_space(1))) unsigned*)(Ahg + (size_t)(row0 + r_ld) * H_ + kt + c_ld),
            (__attribute__((address_space(3))) unsigned*)(Ah + r_ld * 32 + c_ld), 16, 0, 0);
        __builtin_amdgcn_global_load_lds(
            (const __attribute__((address_space(1))) unsigned*)(Alg + (size_t)(row0 + r_ld) * H_ + kt + c_ld),
            (__attribute__((address_space(3))) unsigned*)(Al + r_ld * 32 + c_ld), 16, 0, 0);
        #pragma unroll
        for (int half = 0; half < 2; half++) {
            int r = half * 64 + r_ld;
            __builtin_amdgcn_global_load_lds(
                (const __attribute__((address_space(1))) unsigned*)(Bhg + (size_t)(col0 + r) * H_ + kt + c_ld),
                (__attribute__((address_space(3))) unsigned*)(Bh + r * 32 + c_ld), 16, 0, 0);
            __builtin_amdgcn_global_load_lds(
                (const __attribute__((address_space(1))) unsigned*)(Blg + (size_t)(col0 + r) * H_ + kt + c_ld),
                (__attribute__((address_space(3))) unsigned*)(Bl + r * 32 + c_ld), 16, 0, 0);
        }
        __syncthreads();
        short8 ah[4], al[4], bh[2], bl[2];
        #pragma unroll
        for (int i = 0; i < 4; i++) {
            ah[i] = *(const short8*)(Ah + (i*16 + (lane & 15)) * 32 + (lane >> 4) * 8);
            al[i] = *(const short8*)(Al + (i*16 + (lane & 15)) * 32 + (lane >> 4) * 8);
        }
        #pragma unroll
        for (int j = 0; j < 2; j++) {
            bh[j] = *(const short8*)(Bh + (wave*32 + j*16 + (lane & 15)) * 32 + (lane >> 4) * 8);
            bl[j] = *(const short8*)(Bl + (wave*32 + j*16 + (lane & 15)) * 32 + (lane >> 4) * 8);
        }
        #pragma unroll
        for (int i = 0; i < 4; i++)
            #pragma unroll
            for (int j = 0; j < 2; j++) {
                acc[i][j] = __builtin_amdgcn_mfma_f32_16x16x32_bf16(al[i], bh[j], acc[i][j], 0, 0, 0);
                acc[i][j] = __builtin_amdgcn_mfma_f32_16x16x32_bf16(ah[i], bl[j], acc[i][j], 0, 0, 0);
                acc[i][j] = __builtin_amdgcn_mfma_f32_16x16x32_bf16(ah[i], bh[j], acc[i][j], 0, 0, 0);
            }
        __syncthreads();
    }
    #pragma unroll
    for (int i = 0; i < 4; i++) {
        int row = row0 + i*16 + (lane >> 4) * 4;
        #pragma unroll
        for (int j = 0; j < 2; j++) {
            int col = col0 + wave*32 + j*16 + (lane & 15);
            float bv = bias[col];
            #pragma unroll
            for (int r = 0; r < 4; r++)
                C[(size_t)(row + r) * H_ + col] = acc[i][j][r] + bv;
        }
    }
}

// ---------------- bf16 MFMA GEMM (value path) ----------------
__global__ __launch_bounds__(256) void bgemm_bt_kernel(const short* __restrict__ A,
                                                       const short* __restrict__ B0,
                                                       const short* __restrict__ B1,
                                                       float* __restrict__ C0,
                                                       float* __restrict__ C1,
                                                       const float* __restrict__ bias,
                                                       int N, int K) {
    const short* Bw = (blockIdx.z == 0) ? B0 : B1;
    float*       C  = (blockIdx.z == 0) ? C0 : C1;
    __shared__ short As[128 * 32];
    __shared__ short Bs[128 * 32];
    const int tid  = threadIdx.x;
    const int lane = tid & 63;
    const int wave = tid >> 6;
    const int wr = wave >> 1, wc = wave & 1;
    const int row0 = blockIdx.y * 128, col0 = blockIdx.x * 128;
    const int r_ld = tid >> 2;
    const int c_ld = (tid & 3) * 8;
    f32x4 acc[4][4] = {};
    for (int kt = 0; kt < K; kt += 32) {
        #pragma unroll
        for (int half = 0; half < 2; half++) {
            int r = half * 64 + r_ld;
            __builtin_amdgcn_global_load_lds(
                (const __attribute__((address_space(1))) unsigned*)(A + (size_t)(row0 + r) * K + kt + c_ld),
                (__attribute__((address_space(3))) unsigned*)(As + r * 32 + c_ld), 16, 0, 0);
            __builtin_amdgcn_global_load_lds(
                (const __attribute__((address_space(1))) unsigned*)(Bw + (size_t)(col0 + r) * K + kt + c_ld),
                (__attribute__((address_space(3))) unsigned*)(Bs + r * 32 + c_ld), 16, 0, 0);
        }
        __syncthreads();
        short8 af[4], bfr[4];
        #pragma unroll
        for (int t = 0; t < 4; t++) {
            af[t]  = *(const short8*)(As + (wr*64 + t*16 + (lane & 15)) * 32 + (lane >> 4) * 8);
            bfr[t] = *(const short8*)(Bs + (wc*64 + t*16 + (lane & 15)) * 32 + (lane >> 4) * 8);
        }
        #pragma unroll
        for (int tm = 0; tm < 4; tm++)
            #pragma unroll
            for (int tn = 0; tn < 4; tn++)
                acc[tm][tn] = __builtin_amdgcn_mfma_f32_16x16x32_bf16(af[tm], bfr[tn], acc[tm][tn], 0, 0, 0);
        __syncthreads();
    }
    #pragma unroll
    for (int tm = 0; tm < 4; tm++) {
        int row = row0 + wr*64 + tm*16 + (lane >> 4) * 4;
        #pragma unroll
        for (int tn = 0; tn < 4; tn++) {
            int col = col0 + wc*64 + tn*16 + (lane & 15);
            float bv = bias ? bias[col] : 0.0f;
            #pragma unroll
            for (int r = 0; r < 4; r++)
                C[(size_t)(row + r) * N + col] = acc[tm][tn][r] + bv;
        }
    }
}

// ---------------- top-k radix select (on approximate scores) ----------------
__global__ __launch_bounds__(256) void hist1_kernel(const float* __restrict__ scores,
                                                    unsigned* __restrict__ hist) {
    int i = blockIdx.x * 256 + threadIdx.x;
    if (i >= NSCORE) return;
    int b = i >> 19;
    unsigned key = tokey(scores[i]);
    atomicAdd(&hist[(b << 16) + (key >> 16)], 1u);
}

__global__ __launch_bounds__(256) void hist2_kernel(const float* __restrict__ scores,
                                                    const unsigned* __restrict__ P1,
                                                    unsigned* __restrict__ hist2) {
    int i = blockIdx.x * 256 + threadIdx.x;
    if (i >= NSCORE) return;
    int b = i >> 19;
    unsigned key = tokey(scores[i]);
    if ((key >> 16) == P1[b]) atomicAdd(&hist2[(b << 16) + (key & 0xFFFFu)], 1u);
}

__global__ __launch_bounds__(256) void scan_hist_kernel(const unsigned* __restrict__ hist,
                                                        const unsigned* __restrict__ kin,
                                                        unsigned* __restrict__ binOut,
                                                        unsigned* __restrict__ kOut,
                                                        unsigned kconst) {
    int b = blockIdx.x, tid = threadIdx.x;
    const unsigned* h = hist + ((size_t)b << 16);
    unsigned k = kin ? kin[b] : kconst;
    __shared__ unsigned S[256];
    __shared__ int tstar;
    unsigned s = 0;
    const unsigned* seg = h + tid * 256;
    for (int i = 0; i < 256; i++) s += seg[i];
    S[tid] = s;
    __syncthreads();
    for (int off = 1; off < 256; off <<= 1) {
        unsigned a = S[tid];
        unsigned v = (tid + off < 256) ? S[tid + off] : 0u;
        __syncthreads();
        S[tid] = a + v;
        __syncthreads();
    }
    unsigned St = S[tid];
    unsigned Sn = (tid < 255) ? S[tid + 1] : 0u;
    if (St >= k && (tid == 255 || Sn < k)) tstar = tid;
    __syncthreads();
    if (tid == 0) {
        int t = tstar;
        unsigned runn = (t < 255) ? S[t + 1] : 0u;
        unsigned bin = (unsigned)t * 256u, kprime = 1u;
        for (int i = 255; i >= 0; i--) {
            unsigned c = h[t * 256 + i];
            if (runn + c >= k) { bin = (unsigned)(t * 256 + i); kprime = k - runn; break; }
            runn += c;
        }
        binOut[b] = bin;
        kOut[b]  = kprime;
    }
}

// ---------------- classify: block-owned tiles, NO hot atomics ----------------
// grid (16, 8, 8): hchunk (256 cols), schunk (16 rows), batch. 1024 blocks.
__global__ __launch_bounds__(256) void classify_kernel(const float* __restrict__ scores,
                                                       const unsigned* __restrict__ B1,
                                                       const unsigned* __restrict__ B2,
                                                       unsigned* __restrict__ sel,
                                                       unsigned* __restrict__ partialCnt,
                                                       unsigned* __restrict__ bandN,
                                                       unsigned* __restrict__ bandIdx) {
    const int b  = blockIdx.z;
    const int h0 = blockIdx.x * 256;
    const int s0 = blockIdx.y * 16;
    const int c  = threadIdx.x;
    const float Tf = keytofloat((B1[b] << 16) | B2[b]);
    const float thi = Tf + MARGIN, tlo = Tf - MARGIN;
    unsigned selbit = 0, cnt = 0;
    const float* base = scores + ((size_t)(b * S_ + s0)) * H_ + h0;
    #pragma unroll 4
    for (int j = 0; j < 16; j++) {
        float sv = base[(size_t)j * H_ + c];
        if (sv > thi) { selbit = 1u; cnt++; }
        else if (sv >= tlo) {
            unsigned slot = atomicAdd(&bandN[b], 1u);   // rare (~200/batch total)
            if (slot < BAND_CAP)
                bandIdx[(b << 13) + slot] = (unsigned)(((s0 + j) << 12) | (h0 + c));
        }
    }
    if (selbit) sel[(b << 12) + h0 + c] = 1u;   // benign same-value race across schunks
    __shared__ unsigned red[256];
    red[c] = cnt;
    __syncthreads();
    for (int off = 128; off; off >>= 1) {
        if (c < off) red[c] += red[c + off];
        __syncthreads();
    }
    if (c == 0) partialCnt[b * 128 + blockIdx.y * 16 + blockIdx.x] = red[0];
}

__global__ void finalize_cnt_kernel(const unsigned* __restrict__ partial,
                                    unsigned* __restrict__ certN) {
    int b = threadIdx.x;
    if (b >= B_) return;
    unsigned s = 0;
    for (int i = 0; i < 128; i++) s += partial[b * 128 + i];
    certN[b] = s;
}

// ---------------- exact fp32 score for band entries (one wave each) ----------------
__global__ __launch_bounds__(256) void band_exact_kernel(const float* __restrict__ g,
                                                         const float* __restrict__ w2,
                                                         const float* __restrict__ b2,
                                                         const unsigned* __restrict__ bandN,
                                                         const unsigned* __restrict__ bandIdx,
                                                         float* __restrict__ bandVal) {
    int wid = (blockIdx.x * 256 + threadIdx.x) >> 6;
    int lane = threadIdx.x & 63;
    for (int b = 0; b < B_; b++) {
        int n = bandN[b]; if (n > BAND_CAP) n = BAND_CAP;
        for (int j = wid; j < n; j += 1024) {
            unsigned f = bandIdx[(b << 13) + j];
            int m = b * S_ + (int)(f >> 12);
            int h = (int)(f & (H_ - 1));
            const float* gr = g  + (size_t)m * H_;
            const float* wr = w2 + (size_t)h * H_;
            float s = 0.0f;
            for (int cc = lane * 4; cc < H_; cc += 256) {
                float4 a = *(const float4*)(gr + cc);
                float4 w = *(const float4*)(wr + cc);
                s += a.x*w.x + a.y*w.y + a.z*w.z + a.w*w.w;
            }
            #pragma unroll
            for (int off = 32; off; off >>= 1) s += __shfl_xor(s, off);
            if (lane == 0) bandVal[(b << 13) + j] = s + b2[h];
        }
    }
}

// ---------------- select top-r of band by (exact desc, flat idx asc) ----------------
__global__ __launch_bounds__(256) void band_select_kernel(const float* __restrict__ bandVal,
                                                          const unsigned* __restrict__ bandIdx,
                                                          const unsigned* __restrict__ bandN,
                                                          const unsigned* __restrict__ certainN,
                                                          unsigned* __restrict__ sel) {
    __shared__ float  sv[BAND_CAP];
    __shared__ unsigned si[BAND_CAP];
    int b = blockIdx.x, tid = threadIdx.x;
    int n = bandN[b]; if (n > BAND_CAP) n = BAND_CAP;
    int r = TOPK_K - (int)certainN[b];
    if (r <= 0) return;
    if (r >= n) {
        for (int j = tid; j < n; j += 256)
            sel[(b << 12) + (bandIdx[(b << 13) + j] & (H_ - 1))] = 1u;
        return;
    }
    for (int j = tid; j < n; j += 256) {
        sv[j] = bandVal[(b << 13) + j];
        si[j] = bandIdx[(b << 13) + j];
    }
    __syncthreads();
    for (int j = tid; j < n; j += 256) {
        float vj = sv[j]; unsigned fj = si[j];
        int rank = 0;
        for (int l = 0; l < n; l++) {
            float vl = sv[l]; unsigned fl = si[l];
            rank += (vl > vj) || (vl == vj && fl < fj);
        }
        if (rank < r) sel[(b << 12) + (fj & (H_ - 1))] = 1u;
    }
}

// ---------------- select + bias + exact GELU -> bf16 ----------------
__global__ __launch_bounds__(256) void act_kernel(const float* __restrict__ hprev,
                                                  const float* __restrict__ hcurr,
                                                  const float* __restrict__ bprev,
                                                  const float* __restrict__ bcurr,
                                                  const unsigned* __restrict__ sel,
                                                  __hip_bfloat16* __restrict__ act) {
    int i = blockIdx.x * 256 + threadIdx.x;
    if (i >= NSCORE) return;
    int h = i & (H_ - 1);
    int b = i >> 19;
    float v = sel[(b << 12) + h] ? (hprev[i] + bprev[h]) : (hcurr[i] + bcurr[h]);
    float gl = 0.5f * v * (1.0f + erff(v * 0.70710678118654752440f));
    act[i] = __float2bfloat16(gl);
}

extern "C" void kernel_launch(void* const* d_in, const int* in_sizes, int n_in,
                              void* d_out, int out_size, void* d_ws, size_t ws_size,
                              hipStream_t stream) {
    const float* x     = (const float*)d_in[0];
    const float* wprev = (const float*)d_in[1];
    const float* bprev = (const float*)d_in[2];
    const float* wcurr = (const float*)d_in[3];
    const float* bcurr = (const float*)d_in[4];
    const float* gw1   = (const float*)d_in[5];
    const float* gb1   = (const float*)d_in[6];
    const float* gw2   = (const float*)d_in[7];
    const float* gb2   = (const float*)d_in[8];
    const float* dw    = (const float*)d_in[9];
    const float* db    = (const float*)d_in[10];
    float* out = (float*)d_out;
    char* ws = (char*)d_ws;

    float* g      = (float*)(ws + G_OFF);      // gemm1 partial0, then g
    float* p1     = (float*)(ws + W2H_OFF);    // gemm1 partial1 (before w2 split reuses region)
    float* scores = (float*)(ws + SC_OFF);
    float* hprev  = (float*)(ws + G_OFF);
    float* hcurr  = (float*)(ws + SC_OFF);
    unsigned short* ghi = (unsigned short*)(ws + GHI_OFF);
    unsigned short* glo = (unsigned short*)(ws + GLO_OFF);
    unsigned short* w2h = (unsigned short*)(ws + W2H_OFF);
    unsigned short* w2l = (unsigned short*)(ws + W2L_OFF);
    __hip_bfloat16* xb  = (__hip_bfloat16*)(ws + XB_OFF);
    __hip_bfloat16* wpb = (__hip_bfloat16*)(ws + WPB_OFF);
    __hip_bfloat16* wcb = (__hip_bfloat16*)(ws + WCB_OFF);
    __hip_bfloat16* wdb = (__hip_bfloat16*)(ws + WDB_OFF);
    __hip_bfloat16* act = (__hip_bfloat16*)(ws + ACT_OFF);
    unsigned* hist1   = (unsigned*)(ws + H1_OFF);
    unsigned* hist2   = (unsigned*)(ws + H2_OFF);
    unsigned* sel     = (unsigned*)(ws + SEL_OFF);
    unsigned* certN   = (unsigned*)(ws + CNT_OFF);
    unsigned* bandN   = (unsigned*)(ws + CNT_OFF + 32);
    unsigned* B1c     = (unsigned*)(ws + CNT_OFF + 64);
    unsigned* K1c     = (unsigned*)(ws + CNT_OFF + 96);
    unsigned* B2c     = (unsigned*)(ws + CNT_OFF + 128);
    unsigned* K2c     = (unsigned*)(ws + CNT_OFF + 160);
    unsigned* partCnt = (unsigned*)(ws + PART_OFF);
    unsigned* bandIdx = (unsigned*)(ws + BIDX_OFF);
    float*    bandVal = (float*)(ws + BVAL_OFF);

    // zero: hists, sel+counters (g no longer needs zeroing: plain stores)
    hipMemsetAsync(ws + H1_OFF, 0, 4194304, stream);            // hist1+hist2 contiguous
    hipMemsetAsync(ws + SEL_OFF, 0, 131072 + 512, stream);      // sel + counters + partial hdr

    // gate GEMM1 (fp32, split-K=2, plain stores) then sum+bias+relu+split
    sgemm1_kernel<<<dim3(H_/128, M_/128, 2), 256, 0, stream>>>(x, gw1, g, p1);
    g_post_kernel<<<(M_*H_/4 + 255)/256, 256, 0, stream>>>(g, p1, gb1, ghi, glo);

    // split w2 (overwrites p1 region), then split-bf16 MFMA GEMM2
    split_kernel<<<(H_*H_/4 + 255)/256, 256, 0, stream>>>(gw2, w2h, w2l, H_*H_/4);
    gemm2_split_kernel<<<dim3(H_/128, M_/64), 256, 0, stream>>>(
        (const short*)ghi, (const short*)glo, (const short*)w2h, (const short*)w2l, gb2, scores);

    // value-path bf16 copies (alias w2 split regions -> must follow gemm2)
    f2bf_kernel<<<(M_*D_/4 + 255)/256, 256, 0, stream>>>(x,     xb,  M_*D_/4);
    f2bf_kernel<<<(H_*D_/4 + 255)/256, 256, 0, stream>>>(wprev, wpb, H_*D_/4);
    f2bf_kernel<<<(H_*D_/4 + 255)/256, 256, 0, stream>>>(wcurr, wcb, H_*D_/4);
    f2bf_kernel<<<(H_*D_/4 + 255)/256, 256, 0, stream>>>(dw,    wdb, H_*D_/4);

    // radix threshold on approximate scores
    hist1_kernel<<<NSCORE/256, 256, 0, stream>>>(scores, hist1);
    scan_hist_kernel<<<B_, 256, 0, stream>>>(hist1, nullptr, B1c, K1c, TOPK_K);
    hist2_kernel<<<NSCORE/256, 256, 0, stream>>>(scores, B1c, hist2);
    scan_hist_kernel<<<B_, 256, 0, stream>>>(hist2, K1c, B2c, K2c, 0u);

    // certain marks + band (block-owned, no hot atomics); exact recompute; band top-r
    classify_kernel<<<dim3(16, 8, 8), 256, 0, stream>>>(scores, B1c, B2c, sel, partCnt, bandN, bandIdx);
    finalize_cnt_kernel<<<1, 64, 0, stream>>>(partCnt, certN);
    band_exact_kernel<<<256, 256, 0, stream>>>(g, gw2, gb2, bandN, bandIdx, bandVal);
    band_select_kernel<<<B_, 256, 0, stream>>>(bandVal, bandIdx, bandN, certN, sel);

    // value path
    bgemm_bt_kernel<<<dim3(H_/128, M_/128, 2), 256, 0, stream>>>(
        (const short*)xb, (const short*)wpb, (const short*)wcb, hprev, hcurr, nullptr, H_, D_);
    act_kernel<<<NSCORE/256, 256, 0, stream>>>(hprev, hcurr, bprev, bcurr, sel, act);
    bgemm_bt_kernel<<<dim3(D_/128, M_/128, 1), 256, 0, stream>>>(
        (const short*)act, (const short*)wdb, (const short*)wdb, out, out, db, D_, H_);
}

// Round 4
// 735.209 us; speedup vs baseline: 3.7927x; 1.4291x over previous
//
#include <hip/hip_runtime.h>
#include <hip/hip_bf16.h>

// B=8, S=128, D=1024, H=4096, TOPK=256 -> k = 32768 per batch over S*H=524288 scores.
#define B_  8
#define S_  128
#define D_  1024
#define H_  4096
#define M_  (B_ * S_)          // 1024
#define NSCORE   (M_ * H_)     // 4,194,304
#define PERBATCH (S_ * H_)     // 524,288
#define TOPK_K   (256 * S_)    // 32,768
#define BAND_CAP 8192
#define MARGIN   4e-4f         // split-bf16 score error max ~3e-6 << MARGIN/2

// ---------------- workspace layout (byte offsets) ----------------
#define G_OFF    0u            // gemm1 partial0 / g fp32 [1024,4096] 16MB; later hprev
#define SC_OFF   16777216u     // gemm1 partial1, then scores fp32 16MB; later hcurr
#define GHI_OFF  33554432u     // g_hi bf16 8MB
#define GLO_OFF  41943040u     // g_lo bf16 8MB
#define W2H_OFF  50331648u     // gemm1 partial2+3 (32MB), then w2_hi bf16 32MB; after gemm2: wpb+wcb+xb
#define W2L_OFF  83886080u     // w2_lo bf16 32MB; after gemm2: wdb(8)+act(8)
#define H8_OFF   117440512u    // 8-bit hist: 8 x 256 u32 (8KB)
#define H16_OFF  119537664u    // 16-bit hist: 8 x 65536 u32 (2MB)
#define MISC_OFF 121634816u
#define SEL_OFF  MISC_OFF                 // 8x4096 u32 = 128KB
#define CNT_OFF  (MISC_OFF + 131072u)     // certainN[8], bandN[8], prefix1[8], above1[8], Thi[8], Tlo[8]
#define PART_OFF (MISC_OFF + 131584u)     // per-block certain counts: 1024 u32 (4KB)
#define BIDX_OFF (MISC_OFF + 135680u)     // 8x8192 u32
#define BVAL_OFF (MISC_OFF + 397824u)     // 8x8192 f32
// value-path aliases (valid after gemm2_split has consumed w2 splits)
#define WPB_OFF  W2H_OFF
#define WCB_OFF  (W2H_OFF + 8388608u)
#define XB_OFF   (W2H_OFF + 16777216u)
#define WDB_OFF  W2L_OFF
#define ACT_OFF  (W2L_OFF + 8388608u)
// total ~122.3 MB (same footprint as R3)

typedef __attribute__((ext_vector_type(8))) short short8;
typedef __attribute__((ext_vector_type(4))) float f32x4;

__device__ __forceinline__ unsigned tokey(float f) {
    unsigned u = __float_as_uint(f);
    return (u & 0x80000000u) ? ~u : (u | 0x80000000u);
}
__device__ __forceinline__ float keytofloat(unsigned k) {
    unsigned u = (k & 0x80000000u) ? (k & 0x7FFFFFFFu) : ~k;
    return __uint_as_float(u);
}
__device__ __forceinline__ unsigned short bfbits(float f) {
    __hip_bfloat16 h = __float2bfloat16(f);
    return *(unsigned short*)&h;
}

// ---------------- fp32 -> bf16 convert ----------------
__global__ __launch_bounds__(256) void f2bf_kernel(const float* __restrict__ in,
                                                   __hip_bfloat16* __restrict__ out, int n4) {
    int i = blockIdx.x * 256 + threadIdx.x;
    if (i >= n4) return;
    float4 v = *(const float4*)(in + (size_t)i * 4);
    out[(size_t)i*4+0] = __float2bfloat16(v.x);
    out[(size_t)i*4+1] = __float2bfloat16(v.y);
    out[(size_t)i*4+2] = __float2bfloat16(v.z);
    out[(size_t)i*4+3] = __float2bfloat16(v.w);
}

// ---------------- fp32 -> (hi, lo) bf16 split ----------------
__global__ __launch_bounds__(256) void split_kernel(const float* __restrict__ in,
                                                    unsigned short* __restrict__ hi,
                                                    unsigned short* __restrict__ lo, int n4) {
    int i = blockIdx.x * 256 + threadIdx.x;
    if (i >= n4) return;
    float4 v = *(const float4*)(in + (size_t)i * 4);
    unsigned short h0 = bfbits(v.x), h1 = bfbits(v.y), h2 = bfbits(v.z), h3 = bfbits(v.w);
    ushort4 hv = {h0, h1, h2, h3};
    float r0 = v.x - __bfloat162float(*(__hip_bfloat16*)&h0);
    float r1 = v.y - __bfloat162float(*(__hip_bfloat16*)&h1);
    float r2 = v.z - __bfloat162float(*(__hip_bfloat16*)&h2);
    float r3 = v.w - __bfloat162float(*(__hip_bfloat16*)&h3);
    ushort4 lv = {bfbits(r0), bfbits(r1), bfbits(r2), bfbits(r3)};
    *(ushort4*)(hi + (size_t)i*4) = hv;
    *(ushort4*)(lo + (size_t)i*4) = lv;
}

// ---------------- sum 4 split-K partials + bias + relu + writeback + bf16 split ----------------
__global__ __launch_bounds__(256) void g_post_kernel(float* __restrict__ p0,
                                                     const float* __restrict__ p1,
                                                     const float* __restrict__ p2,
                                                     const float* __restrict__ p3,
                                                     const float* __restrict__ b1,
                                                     unsigned short* __restrict__ hi,
                                                     unsigned short* __restrict__ lo) {
    int i = blockIdx.x * 256 + threadIdx.x;   // over 1M float4s
    if (i >= M_ * H_ / 4) return;
    int j = (i * 4) & (H_ - 1);
    float4 v = *(float4*)(p0 + (size_t)i * 4);
    float4 a = *(const float4*)(p1 + (size_t)i * 4);
    float4 b = *(const float4*)(p2 + (size_t)i * 4);
    float4 c = *(const float4*)(p3 + (size_t)i * 4);
    v.x = fmaxf(v.x + a.x + b.x + c.x + b1[j+0], 0.0f);
    v.y = fmaxf(v.y + a.y + b.y + c.y + b1[j+1], 0.0f);
    v.z = fmaxf(v.z + a.z + b.z + c.z + b1[j+2], 0.0f);
    v.w = fmaxf(v.w + a.w + b.w + c.w + b1[j+3], 0.0f);
    *(float4*)(p0 + (size_t)i * 4) = v;
    unsigned short h0 = bfbits(v.x), h1 = bfbits(v.y), h2 = bfbits(v.z), h3 = bfbits(v.w);
    ushort4 hv = {h0, h1, h2, h3};
    float r0 = v.x - __bfloat162float(*(__hip_bfloat16*)&h0);
    float r1 = v.y - __bfloat162float(*(__hip_bfloat16*)&h1);
    float r2 = v.z - __bfloat162float(*(__hip_bfloat16*)&h2);
    float r3 = v.w - __bfloat162float(*(__hip_bfloat16*)&h3);
    ushort4 lv = {bfbits(r0), bfbits(r1), bfbits(r2), bfbits(r3)};
    *(ushort4*)(hi + (size_t)i*4) = hv;
    *(ushort4*)(lo + (size_t)i*4) = lv;
}

// ---------------- fp32 GEMM1, split-K=4 into separate buffers (no atomics) ----------------
__global__ __launch_bounds__(256) void sgemm1_kernel(const float* __restrict__ A,
                                                     const float* __restrict__ Bm,
                                                     float* __restrict__ P0,
                                                     float* __restrict__ P1,
                                                     float* __restrict__ P2,
                                                     float* __restrict__ P3) {
    __shared__ float As[16][132];
    __shared__ float Bs[16][132];
    float* C = (blockIdx.z == 0) ? P0 : (blockIdx.z == 1) ? P1 : (blockIdx.z == 2) ? P2 : P3;
    const int k0 = blockIdx.z * (D_ / 4);
    const int tid  = threadIdx.x;
    const int row0 = blockIdx.y * 128, col0 = blockIdx.x * 128;
    const int ty = tid >> 4, tx = tid & 15;
    const int r_ld = tid >> 2;
    const int c_ld = (tid & 3) * 4;
    float acc[8][8] = {};
    for (int kt = k0; kt < k0 + D_ / 4; kt += 16) {
        #pragma unroll
        for (int half = 0; half < 2; half++) {
            int r = half * 64 + r_ld;
            float4 va = *(const float4*)(A  + (size_t)(row0 + r) * D_ + kt + c_ld);
            float4 vb = *(const float4*)(Bm + (size_t)(col0 + r) * D_ + kt + c_ld);
            As[c_ld+0][r] = va.x; As[c_ld+1][r] = va.y; As[c_ld+2][r] = va.z; As[c_ld+3][r] = va.w;
            Bs[c_ld+0][r] = vb.x; Bs[c_ld+1][r] = vb.y; Bs[c_ld+2][r] = vb.z; Bs[c_ld+3][r] = vb.w;
        }
        __syncthreads();
        #pragma unroll
        for (int k = 0; k < 16; k++) {
            float a[8], b[8];
            *(float4*)(a)   = *(const float4*)&As[k][ty*8];
            *(float4*)(a+4) = *(const float4*)&As[k][ty*8+4];
            *(float4*)(b)   = *(const float4*)&Bs[k][tx*8];
            *(float4*)(b+4) = *(const float4*)&Bs[k][tx*8+4];
            #pragma unroll
            for (int i = 0; i < 8; i++)
                #pragma unroll
                for (int j = 0; j < 8; j++)
                    acc[i][j] += a[i] * b[j];
        }
        __syncthreads();
    }
    #pragma unroll
    for (int i = 0; i < 8; i++) {
        int row = row0 + ty*8 + i;
        #pragma unroll
        for (int j = 0; j < 8; j++)
            C[(size_t)row * H_ + col0 + tx*8 + j] = acc[i][j];
    }
}

// ---------------- split-bf16 MFMA GEMM2: s = g.w2^T + b2 (3-term hi/lo) ----------------
__global__ __launch_bounds__(256) void gemm2_split_kernel(const short* __restrict__ Ahg,
                                                          const short* __restrict__ Alg,
                                                          const short* __restrict__ Bhg,
                                                          const short* __restrict__ Blg,
                                                          const float* __restrict__ bias,
                                                          float* __restrict__ C) {
    __shared__ short Ah[64*32], Al[64*32], Bh[128*32], Bl[128*32];
    const int tid = threadIdx.x, lane = tid & 63, wave = tid >> 6;
    const int row0 = blockIdx.y * 64, col0 = blockIdx.x * 128;
    const int r_ld = tid >> 2;
    const int c_ld = (tid & 3) * 8;
    f32x4 acc[4][2] = {};
    for (int kt = 0; kt < H_; kt += 32) {
        __builtin_amdgcn_global_load_lds(
            (const __attribute__((address_space(1))) unsigned*)(Ahg + (size_t)(row0 + r_ld) * H_ + kt + c_ld),
            (__attribute__((address_space(3))) unsigned*)(Ah + r_ld * 32 + c_ld), 16, 0, 0);
        __builtin_amdgcn_global_load_lds(
            (const __attribute__((address_space(1))) unsigned*)(Alg + (size_t)(row0 + r_ld) * H_ + kt + c_ld),
            (__attribute__((address_space(3))) unsigned*)(Al + r_ld * 32 + c_ld), 16, 0, 0);
        #pragma unroll
        for (int half = 0; half < 2; half++) {
            int r = half * 64 + r_ld;
            __builtin_amdgcn_global_load_lds(
                (const __attribute__((address_space(1))) unsigned*)(Bhg + (size_t)(col0 + r) * H_ + kt + c_ld),
                (__attribute__((address_space(3))) unsigned*)(Bh + r * 32 + c_ld), 16, 0, 0);
            __builtin_amdgcn_global_load_lds(
                (const __attribute__((address_space(1))) unsigned*)(Blg + (size_t)(col0 + r) * H_ + kt + c_ld),
                (__attribute__((address_space(3))) unsigned*)(Bl + r * 32 + c_ld), 16, 0, 0);
        }
        __syncthreads();
        short8 ah[4], al[4], bh[2], bl[2];
        #pragma unroll
        for (int i = 0; i < 4; i++) {
            ah[i] = *(const short8*)(Ah + (i*16 + (lane & 15)) * 32 + (lane >> 4) * 8);
            al[i] = *(const short8*)(Al + (i*16 + (lane & 15)) * 32 + (lane >> 4) * 8);
        }
        #pragma unroll
        for (int j = 0; j < 2; j++) {
            bh[j] = *(const short8*)(Bh + (wave*32 + j*16 + (lane & 15)) * 32 + (lane >> 4) * 8);
            bl[j] = *(const short8*)(Bl + (wave*32 + j*16 + (lane & 15)) * 32 + (lane >> 4) * 8);
        }
        #pragma unroll
        for (int i = 0; i < 4; i++)
            #pragma unroll
            for (int j = 0; j < 2; j++) {
                acc[i][j] = __builtin_amdgcn_mfma_f32_16x16x32_bf16(al[i], bh[j], acc[i][j], 0, 0, 0);
                acc[i][j] = __builtin_amdgcn_mfma_f32_16x16x32_bf16(ah[i], bl[j], acc[i][j], 0, 0, 0);
                acc[i][j] = __builtin_amdgcn_mfma_f32_16x16x32_bf16(ah[i], bh[j], acc[i][j], 0, 0, 0);
            }
        __syncthreads();
    }
    #pragma unroll
    for (int i = 0; i < 4; i++) {
        int row = row0 + i*16 + (lane >> 4) * 4;
        #pragma unroll
        for (int j = 0; j < 2; j++) {
            int col = col0 + wave*32 + j*16 + (lane & 15);
            float bv = bias[col];
            #pragma unroll
            for (int r = 0; r < 4; r++)
                C[(size_t)(row + r) * H_ + col] = acc[i][j][r] + bv;
        }
    }
}

// ---------------- bf16 MFMA GEMM (value path) ----------------
__global__ __launch_bounds__(256) void bgemm_bt_kernel(const short* __restrict__ A,
                                                       const short* __restrict__ B0,
                                                       const short* __restrict__ B1,
                                                       float* __restrict__ C0,
                                                       float* __restrict__ C1,
                                                       const float* __restrict__ bias,
                                                       int N, int K) {
    const short* Bw = (blockIdx.z == 0) ? B0 : B1;
    float*       C  = (blockIdx.z == 0) ? C0 : C1;
    __shared__ short As[128 * 32];
    __shared__ short Bs[128 * 32];
    const int tid  = threadIdx.x;
    const int lane = tid & 63;
    const int wave = tid >> 6;
    const int wr = wave >> 1, wc = wave & 1;
    const int row0 = blockIdx.y * 128, col0 = blockIdx.x * 128;
    const int r_ld = tid >> 2;
    const int c_ld = (tid & 3) * 8;
    f32x4 acc[4][4] = {};
    for (int kt = 0; kt < K; kt += 32) {
        #pragma unroll
        for (int half = 0; half < 2; half++) {
            int r = half * 64 + r_ld;
            __builtin_amdgcn_global_load_lds(
                (const __attribute__((address_space(1))) unsigned*)(A + (size_t)(row0 + r) * K + kt + c_ld),
                (__attribute__((address_space(3))) unsigned*)(As + r * 32 + c_ld), 16, 0, 0);
            __builtin_amdgcn_global_load_lds(
                (const __attribute__((address_space(1))) unsigned*)(Bw + (size_t)(col0 + r) * K + kt + c_ld),
                (__attribute__((address_space(3))) unsigned*)(Bs + r * 32 + c_ld), 16, 0, 0);
        }
        __syncthreads();
        short8 af[4], bfr[4];
        #pragma unroll
        for (int t = 0; t < 4; t++) {
            af[t]  = *(const short8*)(As + (wr*64 + t*16 + (lane & 15)) * 32 + (lane >> 4) * 8);
            bfr[t] = *(const short8*)(Bs + (wc*64 + t*16 + (lane & 15)) * 32 + (lane >> 4) * 8);
        }
        #pragma unroll
        for (int tm = 0; tm < 4; tm++)
            #pragma unroll
            for (int tn = 0; tn < 4; tn++)
                acc[tm][tn] = __builtin_amdgcn_mfma_f32_16x16x32_bf16(af[tm], bfr[tn], acc[tm][tn], 0, 0, 0);
        __syncthreads();
    }
    #pragma unroll
    for (int tm = 0; tm < 4; tm++) {
        int row = row0 + wr*64 + tm*16 + (lane >> 4) * 4;
        #pragma unroll
        for (int tn = 0; tn < 4; tn++) {
            int col = col0 + wc*64 + tn*16 + (lane & 15);
            float bv = bias ? bias[col] : 0.0f;
            #pragma unroll
            for (int r = 0; r < 4; r++)
                C[(size_t)(row + r) * N + col] = acc[tm][tn][r] + bv;
        }
    }
}

// ---------------- 8-bit LDS-privatized histogram (top byte of key) ----------------
// grid (64, 8): 8192 scores per block, batch = blockIdx.y.
__global__ __launch_bounds__(256) void hist8_kernel(const float* __restrict__ scores,
                                                    unsigned* __restrict__ h8) {
    __shared__ unsigned lh[256];
    const int b = blockIdx.y;
    lh[threadIdx.x] = 0;
    __syncthreads();
    const float* base = scores + ((size_t)b << 19) + (size_t)blockIdx.x * 8192;
    for (int j = threadIdx.x; j < 8192; j += 256) {
        unsigned key = tokey(base[j]);
        atomicAdd(&lh[key >> 24], 1u);
    }
    __syncthreads();
    unsigned v = lh[threadIdx.x];
    if (v) atomicAdd(&h8[(b << 8) + threadIdx.x], v);
}

// one block per batch: find critical top-byte bin (suffix count crosses k)
__global__ __launch_bounds__(256) void scan8_kernel(const unsigned* __restrict__ h8,
                                                    unsigned* __restrict__ prefix1,
                                                    unsigned* __restrict__ above1) {
    int b = blockIdx.x, tid = threadIdx.x;
    __shared__ unsigned S[256];
    __shared__ int tstar;
    S[tid] = h8[(b << 8) + tid];
    __syncthreads();
    for (int off = 1; off < 256; off <<= 1) {
        unsigned a = S[tid];
        unsigned v = (tid + off < 256) ? S[tid + off] : 0u;
        __syncthreads();
        S[tid] = a + v;
        __syncthreads();
    }
    unsigned St = S[tid];
    unsigned Sn = (tid < 255) ? S[tid + 1] : 0u;
    if (St >= TOPK_K && (tid == 255 || Sn < TOPK_K)) tstar = tid;
    __syncthreads();
    if (tid == 0) {
        prefix1[b] = (unsigned)tstar;
        above1[b]  = (tstar < 255) ? S[tstar + 1] : 0u;
    }
}

// 16-bit histogram of bits 23:8 for entries matching the critical top byte
__global__ __launch_bounds__(256) void hist16_kernel(const float* __restrict__ scores,
                                                     const unsigned* __restrict__ prefix1,
                                                     unsigned* __restrict__ h16) {
    int i = blockIdx.x * 256 + threadIdx.x;
    if (i >= NSCORE) return;
    int b = i >> 19;
    unsigned key = tokey(scores[i]);
    if ((key >> 24) == prefix1[b])
        atomicAdd(&h16[((size_t)b << 16) + ((key >> 8) & 0xFFFFu)], 1u);
}

// one block per batch: find critical 24-bit bin, emit float thresholds (bin edges +/- MARGIN)
__global__ __launch_bounds__(256) void scan16_kernel(const unsigned* __restrict__ h16,
                                                     const unsigned* __restrict__ prefix1,
                                                     const unsigned* __restrict__ above1,
                                                     float* __restrict__ Thi,
                                                     float* __restrict__ Tlo) {
    int b = blockIdx.x, tid = threadIdx.x;
    const unsigned* h = h16 + ((size_t)b << 16);
    unsigned k = TOPK_K - above1[b];     // >= 1 by construction
    __shared__ unsigned S[256];
    __shared__ int tstar;
    unsigned s = 0;
    const unsigned* seg = h + tid * 256;
    for (int i = 0; i < 256; i++) s += seg[i];
    S[tid] = s;
    __syncthreads();
    for (int off = 1; off < 256; off <<= 1) {
        unsigned a = S[tid];
        unsigned v = (tid + off < 256) ? S[tid + off] : 0u;
        __syncthreads();
        S[tid] = a + v;
        __syncthreads();
    }
    unsigned St = S[tid];
    unsigned Sn = (tid < 255) ? S[tid + 1] : 0u;
    if (St >= k && (tid == 255 || Sn < k)) tstar = tid;
    __syncthreads();
    if (tid == 0) {
        int t = tstar;
        unsigned runn = (t < 255) ? S[t + 1] : 0u;
        unsigned c = (unsigned)t * 256u;
        for (int i = 255; i >= 0; i--) {
            unsigned cc = h[t * 256 + i];
            if (runn + cc >= k) { c = (unsigned)(t * 256 + i); break; }
            runn += cc;
        }
        unsigned P24 = (prefix1[b] << 16) | c;
        // guard the negative-NaN key zone (keys < 0x00800000); unreachable in practice
        float tlo = (P24 < 0x8000u) ? -INFINITY : keytofloat(P24 << 8);
        float thi = (P24 == 0x00FFFFFFu) ? INFINITY
                  : ((P24 + 1u) < 0x8000u ? -INFINITY : keytofloat((P24 + 1u) << 8));
        Thi[b] = thi + MARGIN;
        Tlo[b] = tlo - MARGIN;
    }
}

// ---------------- classify: block-owned tiles, NO hot atomics ----------------
// grid (16, 8, 8): hchunk (256 cols), schunk (16 rows), batch.
__global__ __launch_bounds__(256) void classify_kernel(const float* __restrict__ scores,
                                                       const float* __restrict__ Thi,
                                                       const float* __restrict__ Tlo,
                                                       unsigned* __restrict__ sel,
                                                       unsigned* __restrict__ partialCnt,
                                                       unsigned* __restrict__ bandN,
                                                       unsigned* __restrict__ bandIdx) {
    const int b  = blockIdx.z;
    const int h0 = blockIdx.x * 256;
    const int s0 = blockIdx.y * 16;
    const int c  = threadIdx.x;
    const float thi = Thi[b], tlo = Tlo[b];
    unsigned selbit = 0, cnt = 0;
    const float* base = scores + ((size_t)(b * S_ + s0)) * H_ + h0;
    #pragma unroll 4
    for (int j = 0; j < 16; j++) {
        float sv = base[(size_t)j * H_ + c];
        if (sv > thi) { selbit = 1u; cnt++; }
        else if (sv >= tlo) {
            unsigned slot = atomicAdd(&bandN[b], 1u);   // rare (~300/batch)
            if (slot < BAND_CAP)
                bandIdx[(b << 13) + slot] = (unsigned)(((s0 + j) << 12) | (h0 + c));
        }
    }
    if (selbit) sel[(b << 12) + h0 + c] = 1u;   // benign same-value race across schunks
    __shared__ unsigned red[256];
    red[c] = cnt;
    __syncthreads();
    for (int off = 128; off; off >>= 1) {
        if (c < off) red[c] += red[c + off];
        __syncthreads();
    }
    if (c == 0) partialCnt[b * 128 + blockIdx.y * 16 + blockIdx.x] = red[0];
}

__global__ void finalize_cnt_kernel(const unsigned* __restrict__ partial,
                                    unsigned* __restrict__ certN) {
    int b = threadIdx.x;
    if (b >= B_) return;
    unsigned s = 0;
    for (int i = 0; i < 128; i++) s += partial[b * 128 + i];
    certN[b] = s;
}

// ---------------- exact fp32 score for band entries (one wave each) ----------------
__global__ __launch_bounds__(256) void band_exact_kernel(const float* __restrict__ g,
                                                         const float* __restrict__ w2,
                                                         const float* __restrict__ b2,
                                                         const unsigned* __restrict__ bandN,
                                                         const unsigned* __restrict__ bandIdx,
                                                         float* __restrict__ bandVal) {
    int wid = (blockIdx.x * 256 + threadIdx.x) >> 6;
    int lane = threadIdx.x & 63;
    for (int b = 0; b < B_; b++) {
        int n = bandN[b]; if (n > BAND_CAP) n = BAND_CAP;
        for (int j = wid; j < n; j += 1024) {
            unsigned f = bandIdx[(b << 13) + j];
            int m = b * S_ + (int)(f >> 12);
            int h = (int)(f & (H_ - 1));
            const float* gr = g  + (size_t)m * H_;
            const float* wr = w2 + (size_t)h * H_;
            float s = 0.0f;
            for (int cc = lane * 4; cc < H_; cc += 256) {
                float4 a = *(const float4*)(gr + cc);
                float4 w = *(const float4*)(wr + cc);
                s += a.x*w.x + a.y*w.y + a.z*w.z + a.w*w.w;
            }
            #pragma unroll
            for (int off = 32; off; off >>= 1) s += __shfl_xor(s, off);
            if (lane == 0) bandVal[(b << 13) + j] = s + b2[h];
        }
    }
}

// ---------------- select top-r of band by (exact desc, flat idx asc) ----------------
__global__ __launch_bounds__(256) void band_select_kernel(const float* __restrict__ bandVal,
                                                          const unsigned* __restrict__ bandIdx,
                                                          const unsigned* __restrict__ bandN,
                                                          const unsigned* __restrict__ certainN,
                                                          unsigned* __restrict__ sel) {
    __shared__ float  sv[BAND_CAP];
    __shared__ unsigned si[BAND_CAP];
    int b = blockIdx.x, tid = threadIdx.x;
    int n = bandN[b]; if (n > BAND_CAP) n = BAND_CAP;
    int r = TOPK_K - (int)certainN[b];
    if (r <= 0) return;
    if (r >= n) {
        for (int j = tid; j < n; j += 256)
            sel[(b << 12) + (bandIdx[(b << 13) + j] & (H_ - 1))] = 1u;
        return;
    }
    for (int j = tid; j < n; j += 256) {
        sv[j] = bandVal[(b << 13) + j];
        si[j] = bandIdx[(b << 13) + j];
    }
    __syncthreads();
    for (int j = tid; j < n; j += 256) {
        float vj = sv[j]; unsigned fj = si[j];
        int rank = 0;
        for (int l = 0; l < n; l++) {
            float vl = sv[l]; unsigned fl = si[l];
            rank += (vl > vj) || (vl == vj && fl < fj);
        }
        if (rank < r) sel[(b << 12) + (fj & (H_ - 1))] = 1u;
    }
}

// ---------------- select + bias + exact GELU -> bf16 ----------------
__global__ __launch_bounds__(256) void act_kernel(const float* __restrict__ hprev,
                                                  const float* __restrict__ hcurr,
                                                  const float* __restrict__ bprev,
                                                  const float* __restrict__ bcurr,
                                                  const unsigned* __restrict__ sel,
                                                  __hip_bfloat16* __restrict__ act) {
    int i = blockIdx.x * 256 + threadIdx.x;
    if (i >= NSCORE) return;
    int h = i & (H_ - 1);
    int b = i >> 19;
    float v = sel[(b << 12) + h] ? (hprev[i] + bprev[h]) : (hcurr[i] + bcurr[h]);
    float gl = 0.5f * v * (1.0f + erff(v * 0.70710678118654752440f));
    act[i] = __float2bfloat16(gl);
}

extern "C" void kernel_launch(void* const* d_in, const int* in_sizes, int n_in,
                              void* d_out, int out_size, void* d_ws, size_t ws_size,
                              hipStream_t stream) {
    const float* x     = (const float*)d_in[0];
    const float* wprev = (const float*)d_in[1];
    const float* bprev = (const float*)d_in[2];
    const float* wcurr = (const float*)d_in[3];
    const float* bcurr = (const float*)d_in[4];
    const float* gw1   = (const float*)d_in[5];
    const float* gb1   = (const float*)d_in[6];
    const float* gw2   = (const float*)d_in[7];
    const float* gb2   = (const float*)d_in[8];
    const float* dw    = (const float*)d_in[9];
    const float* db    = (const float*)d_in[10];
    float* out = (float*)d_out;
    char* ws = (char*)d_ws;

    float* g      = (float*)(ws + G_OFF);           // partial0, then g
    float* p1     = (float*)(ws + SC_OFF);          // partial1 (scores region, free pre-gemm2)
    float* p2     = (float*)(ws + W2H_OFF);         // partial2 (w2h region, free pre-split)
    float* p3     = (float*)(ws + W2H_OFF + 16777216u); // partial3
    float* scores = (float*)(ws + SC_OFF);
    float* hprev  = (float*)(ws + G_OFF);
    float* hcurr  = (float*)(ws + SC_OFF);
    unsigned short* ghi = (unsigned short*)(ws + GHI_OFF);
    unsigned short* glo = (unsigned short*)(ws + GLO_OFF);
    unsigned short* w2h = (unsigned short*)(ws + W2H_OFF);
    unsigned short* w2l = (unsigned short*)(ws + W2L_OFF);
    __hip_bfloat16* xb  = (__hip_bfloat16*)(ws + XB_OFF);
    __hip_bfloat16* wpb = (__hip_bfloat16*)(ws + WPB_OFF);
    __hip_bfloat16* wcb = (__hip_bfloat16*)(ws + WCB_OFF);
    __hip_bfloat16* wdb = (__hip_bfloat16*)(ws + WDB_OFF);
    __hip_bfloat16* act = (__hip_bfloat16*)(ws + ACT_OFF);
    unsigned* h8      = (unsigned*)(ws + H8_OFF);
    unsigned* h16     = (unsigned*)(ws + H16_OFF);
    unsigned* sel     = (unsigned*)(ws + SEL_OFF);
    unsigned* certN   = (unsigned*)(ws + CNT_OFF);
    unsigned* bandN   = (unsigned*)(ws + CNT_OFF + 32);
    unsigned* prefix1 = (unsigned*)(ws + CNT_OFF + 64);
    unsigned* above1  = (unsigned*)(ws + CNT_OFF + 96);
    float*    Thi     = (float*)(ws + CNT_OFF + 128);
    float*    Tlo     = (float*)(ws + CNT_OFF + 160);
    unsigned* partCnt = (unsigned*)(ws + PART_OFF);
    unsigned* bandIdx = (unsigned*)(ws + BIDX_OFF);
    float*    bandVal = (float*)(ws + BVAL_OFF);

    // zero: h8 (8KB), h16 (2MB), sel+counters
    hipMemsetAsync(ws + H8_OFF, 0, 8192, stream);
    hipMemsetAsync(ws + H16_OFF, 0, 2097152, stream);
    hipMemsetAsync(ws + SEL_OFF, 0, 131072 + 512, stream);

    // gate GEMM1 (fp32, split-K=4, plain stores) then sum+bias+relu+split
    sgemm1_kernel<<<dim3(H_/128, M_/128, 4), 256, 0, stream>>>(x, gw1, g, p1, p2, p3);
    g_post_kernel<<<(M_*H_/4 + 255)/256, 256, 0, stream>>>(g, p1, p2, p3, gb1, ghi, glo);

    // split w2 (overwrites p2/p3 region), then split-bf16 MFMA GEMM2 (overwrites p1/scores)
    split_kernel<<<(H_*H_/4 + 255)/256, 256, 0, stream>>>(gw2, w2h, w2l, H_*H_/4);
    gemm2_split_kernel<<<dim3(H_/128, M_/64), 256, 0, stream>>>(
        (const short*)ghi, (const short*)glo, (const short*)w2h, (const short*)w2l, gb2, scores);

    // value-path bf16 copies (alias w2 split regions -> must follow gemm2)
    f2bf_kernel<<<(M_*D_/4 + 255)/256, 256, 0, stream>>>(x,     xb,  M_*D_/4);
    f2bf_kernel<<<(H_*D_/4 + 255)/256, 256, 0, stream>>>(wprev, wpb, H_*D_/4);
    f2bf_kernel<<<(H_*D_/4 + 255)/256, 256, 0, stream>>>(wcurr, wcb, H_*D_/4);
    f2bf_kernel<<<(H_*D_/4 + 255)/256, 256, 0, stream>>>(dw,    wdb, H_*D_/4);

    // threshold: 8-bit LDS hist -> critical byte -> 16-bit hist of that byte -> bin-edge thresholds
    hist8_kernel<<<dim3(64, 8), 256, 0, stream>>>(scores, h8);
    scan8_kernel<<<B_, 256, 0, stream>>>(h8, prefix1, above1);
    hist16_kernel<<<NSCORE/256, 256, 0, stream>>>(scores, prefix1, h16);
    scan16_kernel<<<B_, 256, 0, stream>>>(h16, prefix1, above1, Thi, Tlo);

    // certain marks + band (block-owned); exact recompute; band top-r
    classify_kernel<<<dim3(16, 8, 8), 256, 0, stream>>>(scores, Thi, Tlo, sel, partCnt, bandN, bandIdx);
    finalize_cnt_kernel<<<1, 64, 0, stream>>>(partCnt, certN);
    band_exact_kernel<<<256, 256, 0, stream>>>(g, gw2, gb2, bandN, bandIdx, bandVal);
    band_select_kernel<<<B_, 256, 0, stream>>>(bandVal, bandIdx, bandN, certN, sel);

    // value path
    bgemm_bt_kernel<<<dim3(H_/128, M_/128, 2), 256, 0, stream>>>(
        (const short*)xb, (const short*)wpb, (const short*)wcb, hprev, hcurr, nullptr, H_, D_);
    act_kernel<<<NSCORE/256, 256, 0, stream>>>(hprev, hcurr, bprev, bcurr, sel, act);
    bgemm_bt_kernel<<<dim3(D_/128, M_/128, 1), 256, 0, stream>>>(
        (const short*)act, (const short*)wdb, (const short*)wdb, out, out, db, D_, H_);
}

// Round 5
// 545.191 us; speedup vs baseline: 5.1146x; 1.3485x over previous
//
#include <hip/hip_runtime.h>
#include <hip/hip_bf16.h>

// B=8, S=128, D=1024, H=4096, TOPK=256 -> k = 32768 per batch over S*H=524288 scores.
#define B_  8
#define S_  128
#define D_  1024
#define H_  4096
#define M_  (B_ * S_)          // 1024
#define NSCORE   (M_ * H_)     // 4,194,304
#define PERBATCH (S_ * H_)     // 524,288
#define TOPK_K   (256 * S_)    // 32,768
#define BAND_CAP 8192
#define MARGIN   4e-4f         // total split-bf16 score error max ~1e-5 << MARGIN

#define AS1 __attribute__((address_space(1)))
#define AS3 __attribute__((address_space(3)))

// ---------------- workspace layout (byte offsets) ----------------
#define G_OFF    0u            // g fp32 [1024,4096] 16MB; later hprev
#define SC_OFF   16777216u     // scores fp32 16MB; later hcurr
#define GHI_OFF  33554432u     // ghi bf16 8MB; later down partials 0,1
#define GLO_OFF  41943040u     // glo bf16 8MB; later down partials 2,3
#define XHI_OFF  50331648u     // x hi bf16 2MB (doubles as value-path xb)
#define XLO_OFF  52428800u     // x lo bf16 2MB
#define W1H_OFF  54525952u     // w1 hi 8MB (aliases w2h head; dead after gemm1)
#define W1L_OFF  62914560u     // w1 lo 8MB
#define W2H_OFF  54525952u     // w2 hi 32MB (52M..84M); after gemm2: wpb/wcb/wdb/act
#define W2L_OFF  88080384u     // w2 lo 32MB (84M..116M)
#define WPB_OFF  54525952u     // 8MB
#define WCB_OFF  62914560u     // 8MB
#define WDB_OFF  71303168u     // 8MB
#define ACT_OFF  79691776u     // 8MB (ends 84M)
#define H8_OFF   121634816u    // 8x256 u32 (+pad to 64KB)
#define H16_OFF  121700352u    // 8x65536 u32 (2MB)
#define SEL_OFF  123797504u    // 8x4096 u32 (128KB)
#define CNT_OFF  123928576u    // certN[8],bandN[8],prefix1[8],above1[8],Thi[8],Tlo[8]
#define PART_OFF 123929088u    // 1024 u32
#define BIDX_OFF 123933184u    // 8x8192 u32
#define BVAL_OFF 124195328u    // 8x8192 f32
// end ~124.5 MB (< R4's proven 122.3+?  R4 end was ~122.3MB; this adds ~2MB — still well
// inside the harness workspace that has accommodated every round so far)

typedef __attribute__((ext_vector_type(8))) short short8;
typedef __attribute__((ext_vector_type(4))) float f32x4;

__device__ __forceinline__ unsigned tokey(float f) {
    unsigned u = __float_as_uint(f);
    return (u & 0x80000000u) ? ~u : (u | 0x80000000u);
}
__device__ __forceinline__ float keytofloat(unsigned k) {
    unsigned u = (k & 0x80000000u) ? (k & 0x7FFFFFFFu) : ~k;
    return __uint_as_float(u);
}
__device__ __forceinline__ unsigned short bfbits(float f) {
    __hip_bfloat16 h = __float2bfloat16(f);
    return *(unsigned short*)&h;
}

// ---------------- fp32 -> (hi, lo) bf16 split ----------------
__global__ __launch_bounds__(256) void split_kernel(const float* __restrict__ in,
                                                    unsigned short* __restrict__ hi,
                                                    unsigned short* __restrict__ lo, int n4) {
    int i = blockIdx.x * 256 + threadIdx.x;
    if (i >= n4) return;
    float4 v = *(const float4*)(in + (size_t)i * 4);
    unsigned short h0 = bfbits(v.x), h1 = bfbits(v.y), h2 = bfbits(v.z), h3 = bfbits(v.w);
    ushort4 hv = {h0, h1, h2, h3};
    float r0 = v.x - __bfloat162float(*(__hip_bfloat16*)&h0);
    float r1 = v.y - __bfloat162float(*(__hip_bfloat16*)&h1);
    float r2 = v.z - __bfloat162float(*(__hip_bfloat16*)&h2);
    float r3 = v.w - __bfloat162float(*(__hip_bfloat16*)&h3);
    ushort4 lv = {bfbits(r0), bfbits(r1), bfbits(r2), bfbits(r3)};
    *(ushort4*)(hi + (size_t)i*4) = hv;
    *(ushort4*)(lo + (size_t)i*4) = lv;
}

// ---------------- three fp32 -> bf16 conversions in one launch ----------------
__global__ __launch_bounds__(256) void f2bf3_kernel(const float* __restrict__ s0,
                                                    const float* __restrict__ s1,
                                                    const float* __restrict__ s2,
                                                    unsigned short* __restrict__ d0,
                                                    unsigned short* __restrict__ d1,
                                                    unsigned short* __restrict__ d2) {
    const int Q = H_ * D_ / 4;
    int i = blockIdx.x * 256 + threadIdx.x;     // grid = 3*Q threads exactly
    int w = i / Q, j = i - w * Q;
    const float* s = (w == 0) ? s0 : (w == 1) ? s1 : s2;
    unsigned short* d = (w == 0) ? d0 : (w == 1) ? d1 : d2;
    float4 v = *(const float4*)(s + (size_t)j * 4);
    ushort4 o = {bfbits(v.x), bfbits(v.y), bfbits(v.z), bfbits(v.w)};
    *(ushort4*)(d + (size_t)j * 4) = o;
}

// ---------------- split-bf16 MFMA GEMM (3-term hi/lo), 64x128 tile, BK=64, swizzled LDS ----
// A [M,K] hi/lo, B [N,K] hi/lo (B^T operand), N fixed = 4096. Grid (32, M/64).
// EPI=0: C = acc + bias (scores). EPI=1: v=relu(acc+bias); C=v; hi/lo = bf16 split of v.
// Swizzle: LDS slot l holds global colblock (l&7)^(r&7) of row r=l>>3 -> fragment reads
// spread over all 32 banks (was 8-way conflict on banks {0,16}).
template <int EPI>
__global__ __launch_bounds__(256) void gemm_split_kernel(const short* __restrict__ Ahg,
                                                         const short* __restrict__ Alg,
                                                         const short* __restrict__ Bhg,
                                                         const short* __restrict__ Blg,
                                                         const float* __restrict__ bias,
                                                         int K,
                                                         float* __restrict__ C,
                                                         unsigned short* __restrict__ hi,
                                                         unsigned short* __restrict__ lo) {
    __shared__ short lAh[64*64], lAl[64*64], lBh[128*64], lBl[128*64];   // 48 KB
    const int tid = threadIdx.x, lane = tid & 63, wave = tid >> 6;
    const int row0 = blockIdx.y * 64, col0 = blockIdx.x * 128;
    f32x4 acc[4][2] = {};
    for (int kt = 0; kt < K; kt += 64) {
        #pragma unroll
        for (int q = 0; q < 2; q++) {
            int l = q * 256 + tid;
            int r = l >> 3, cg = ((l & 7) ^ (r & 7)) * 8;
            size_t go = (size_t)(row0 + r) * K + kt + cg;
            __builtin_amdgcn_global_load_lds((const AS1 unsigned*)(Ahg + go),
                (AS3 unsigned*)(lAh + l * 8), 16, 0, 0);
            __builtin_amdgcn_global_load_lds((const AS1 unsigned*)(Alg + go),
                (AS3 unsigned*)(lAl + l * 8), 16, 0, 0);
        }
        #pragma unroll
        for (int q = 0; q < 4; q++) {
            int l = q * 256 + tid;
            int r = l >> 3, cg = ((l & 7) ^ (r & 7)) * 8;
            size_t go = (size_t)(col0 + r) * K + kt + cg;
            __builtin_amdgcn_global_load_lds((const AS1 unsigned*)(Bhg + go),
                (AS3 unsigned*)(lBh + l * 8), 16, 0, 0);
            __builtin_amdgcn_global_load_lds((const AS1 unsigned*)(Blg + go),
                (AS3 unsigned*)(lBl + l * 8), 16, 0, 0);
        }
        __syncthreads();
        #pragma unroll
        for (int kk = 0; kk < 2; kk++) {
            const int cb = kk * 4 + (lane >> 4);
            short8 ah[4], al[4], bh[2], bl[2];
            #pragma unroll
            for (int i = 0; i < 4; i++) {
                int r = i * 16 + (lane & 15);
                int s = (r * 8 + (cb ^ (r & 7))) * 8;
                ah[i] = *(const short8*)(lAh + s);
                al[i] = *(const short8*)(lAl + s);
            }
            #pragma unroll
            for (int j = 0; j < 2; j++) {
                int r = wave * 32 + j * 16 + (lane & 15);
                int s = (r * 8 + (cb ^ (r & 7))) * 8;
                bh[j] = *(const short8*)(lBh + s);
                bl[j] = *(const short8*)(lBl + s);
            }
            #pragma unroll
            for (int i = 0; i < 4; i++)
                #pragma unroll
                for (int j = 0; j < 2; j++) {
                    acc[i][j] = __builtin_amdgcn_mfma_f32_16x16x32_bf16(al[i], bh[j], acc[i][j], 0, 0, 0);
                    acc[i][j] = __builtin_amdgcn_mfma_f32_16x16x32_bf16(ah[i], bl[j], acc[i][j], 0, 0, 0);
                    acc[i][j] = __builtin_amdgcn_mfma_f32_16x16x32_bf16(ah[i], bh[j], acc[i][j], 0, 0, 0);
                }
        }
        __syncthreads();
    }
    #pragma unroll
    for (int i = 0; i < 4; i++) {
        int row = row0 + i * 16 + (lane >> 4) * 4;
        #pragma unroll
        for (int j = 0; j < 2; j++) {
            int col = col0 + wave * 32 + j * 16 + (lane & 15);
            float bv = bias[col];
            #pragma unroll
            for (int r = 0; r < 4; r++) {
                float v = acc[i][j][r] + bv;
                size_t o = (size_t)(row + r) * H_ + col;
                if (EPI == 1) {
                    v = fmaxf(v, 0.0f);
                    C[o] = v;
                    unsigned short hb = bfbits(v);
                    hi[o] = hb;
                    lo[o] = bfbits(v - __bfloat162float(*(__hip_bfloat16*)&hb));
                } else {
                    C[o] = v;
                }
            }
        }
    }
}

// ---------------- bf16 MFMA GEMM, value path up-proj (both weights in one launch) --------
__global__ __launch_bounds__(256) void bgemm_bt_kernel(const short* __restrict__ A,
                                                       const short* __restrict__ B0,
                                                       const short* __restrict__ B1,
                                                       float* __restrict__ C0,
                                                       float* __restrict__ C1,
                                                       int N, int K) {
    const short* Bw = (blockIdx.z == 0) ? B0 : B1;
    float*       C  = (blockIdx.z == 0) ? C0 : C1;
    __shared__ short As[128 * 32];
    __shared__ short Bs[128 * 32];
    const int tid = threadIdx.x, lane = tid & 63, wave = tid >> 6;
    const int wr = wave >> 1, wc = wave & 1;
    const int row0 = blockIdx.y * 128, col0 = blockIdx.x * 128;
    const int r_ld = tid >> 2, c_ld = (tid & 3) * 8;
    f32x4 acc[4][4] = {};
    for (int kt = 0; kt < K; kt += 32) {
        #pragma unroll
        for (int half = 0; half < 2; half++) {
            int r = half * 64 + r_ld;
            __builtin_amdgcn_global_load_lds(
                (const AS1 unsigned*)(A + (size_t)(row0 + r) * K + kt + c_ld),
                (AS3 unsigned*)(As + r * 32 + c_ld), 16, 0, 0);
            __builtin_amdgcn_global_load_lds(
                (const AS1 unsigned*)(Bw + (size_t)(col0 + r) * K + kt + c_ld),
                (AS3 unsigned*)(Bs + r * 32 + c_ld), 16, 0, 0);
        }
        __syncthreads();
        short8 af[4], bfr[4];
        #pragma unroll
        for (int t = 0; t < 4; t++) {
            af[t]  = *(const short8*)(As + (wr*64 + t*16 + (lane & 15)) * 32 + (lane >> 4) * 8);
            bfr[t] = *(const short8*)(Bs + (wc*64 + t*16 + (lane & 15)) * 32 + (lane >> 4) * 8);
        }
        #pragma unroll
        for (int tm = 0; tm < 4; tm++)
            #pragma unroll
            for (int tn = 0; tn < 4; tn++)
                acc[tm][tn] = __builtin_amdgcn_mfma_f32_16x16x32_bf16(af[tm], bfr[tn], acc[tm][tn], 0, 0, 0);
        __syncthreads();
    }
    #pragma unroll
    for (int tm = 0; tm < 4; tm++) {
        int row = row0 + wr*64 + tm*16 + (lane >> 4) * 4;
        #pragma unroll
        for (int tn = 0; tn < 4; tn++) {
            int col = col0 + wc*64 + tn*16 + (lane & 15);
            #pragma unroll
            for (int r = 0; r < 4; r++)
                C[(size_t)(row + r) * N + col] = acc[tm][tn][r];
        }
    }
}

// ---------------- down-proj with split-K=4 into partial buffers ----------------
__global__ __launch_bounds__(256) void bgemm_down_kernel(const short* __restrict__ A,
                                                         const short* __restrict__ Bw,
                                                         float* __restrict__ P) {
    __shared__ short As[128 * 32];
    __shared__ short Bs[128 * 32];
    const int tid = threadIdx.x, lane = tid & 63, wave = tid >> 6;
    const int wr = wave >> 1, wc = wave & 1;
    const int row0 = blockIdx.y * 128, col0 = blockIdx.x * 128;
    const int k0 = blockIdx.z * (H_ / 4);
    float* C = P + (size_t)blockIdx.z * (M_ * D_);
    const int r_ld = tid >> 2, c_ld = (tid & 3) * 8;
    f32x4 acc[4][4] = {};
    for (int kt = k0; kt < k0 + H_ / 4; kt += 32) {
        #pragma unroll
        for (int half = 0; half < 2; half++) {
            int r = half * 64 + r_ld;
            __builtin_amdgcn_global_load_lds(
                (const AS1 unsigned*)(A + (size_t)(row0 + r) * H_ + kt + c_ld),
                (AS3 unsigned*)(As + r * 32 + c_ld), 16, 0, 0);
            __builtin_amdgcn_global_load_lds(
                (const AS1 unsigned*)(Bw + (size_t)(col0 + r) * H_ + kt + c_ld),
                (AS3 unsigned*)(Bs + r * 32 + c_ld), 16, 0, 0);
        }
        __syncthreads();
        short8 af[4], bfr[4];
        #pragma unroll
        for (int t = 0; t < 4; t++) {
            af[t]  = *(const short8*)(As + (wr*64 + t*16 + (lane & 15)) * 32 + (lane >> 4) * 8);
            bfr[t] = *(const short8*)(Bs + (wc*64 + t*16 + (lane & 15)) * 32 + (lane >> 4) * 8);
        }
        #pragma unroll
        for (int tm = 0; tm < 4; tm++)
            #pragma unroll
            for (int tn = 0; tn < 4; tn++)
                acc[tm][tn] = __builtin_amdgcn_mfma_f32_16x16x32_bf16(af[tm], bfr[tn], acc[tm][tn], 0, 0, 0);
        __syncthreads();
    }
    #pragma unroll
    for (int tm = 0; tm < 4; tm++) {
        int row = row0 + wr*64 + tm*16 + (lane >> 4) * 4;
        #pragma unroll
        for (int tn = 0; tn < 4; tn++) {
            int col = col0 + wc*64 + tn*16 + (lane & 15);
            #pragma unroll
            for (int r = 0; r < 4; r++)
                C[(size_t)(row + r) * D_ + col] = acc[tm][tn][r];
        }
    }
}

__global__ __launch_bounds__(256) void down_merge_kernel(const float* __restrict__ P,
                                                         const float* __restrict__ db,
                                                         float* __restrict__ out) {
    int i = blockIdx.x * 256 + threadIdx.x;    // over 262144 float4s
    if (i >= M_ * D_ / 4) return;
    int col = (i * 4) & (D_ - 1);
    float4 a = *(const float4*)(P + (size_t)i * 4);
    float4 b = *(const float4*)(P + (size_t)(M_*D_) + (size_t)i * 4);
    float4 c = *(const float4*)(P + (size_t)(2*M_*D_) + (size_t)i * 4);
    float4 d = *(const float4*)(P + (size_t)(3*M_*D_) + (size_t)i * 4);
    float4 o;
    o.x = a.x + b.x + c.x + d.x + db[col+0];
    o.y = a.y + b.y + c.y + d.y + db[col+1];
    o.z = a.z + b.z + c.z + d.z + db[col+2];
    o.w = a.w + b.w + c.w + d.w + db[col+3];
    *(float4*)(out + (size_t)i * 4) = o;
}

// ---------------- 8-bit LDS-privatized histogram (top byte of key) ----------------
__global__ __launch_bounds__(256) void hist8_kernel(const float* __restrict__ scores,
                                                    unsigned* __restrict__ h8) {
    __shared__ unsigned lh[256];
    const int b = blockIdx.y;
    lh[threadIdx.x] = 0;
    __syncthreads();
    const float* base = scores + ((size_t)b << 19) + (size_t)blockIdx.x * 8192;
    for (int j = threadIdx.x; j < 8192; j += 256) {
        unsigned key = tokey(base[j]);
        atomicAdd(&lh[key >> 24], 1u);
    }
    __syncthreads();
    unsigned v = lh[threadIdx.x];
    if (v) atomicAdd(&h8[(b << 8) + threadIdx.x], v);
}

__global__ __launch_bounds__(256) void scan8_kernel(const unsigned* __restrict__ h8,
                                                    unsigned* __restrict__ prefix1,
                                                    unsigned* __restrict__ above1) {
    int b = blockIdx.x, tid = threadIdx.x;
    __shared__ unsigned S[256];
    __shared__ int tstar;
    S[tid] = h8[(b << 8) + tid];
    __syncthreads();
    for (int off = 1; off < 256; off <<= 1) {
        unsigned a = S[tid];
        unsigned v = (tid + off < 256) ? S[tid + off] : 0u;
        __syncthreads();
        S[tid] = a + v;
        __syncthreads();
    }
    unsigned St = S[tid];
    unsigned Sn = (tid < 255) ? S[tid + 1] : 0u;
    if (St >= TOPK_K && (tid == 255 || Sn < TOPK_K)) tstar = tid;
    __syncthreads();
    if (tid == 0) {
        prefix1[b] = (unsigned)tstar;
        above1[b]  = (tstar < 255) ? S[tstar + 1] : 0u;
    }
}

__global__ __launch_bounds__(256) void hist16_kernel(const float* __restrict__ scores,
                                                     const unsigned* __restrict__ prefix1,
                                                     unsigned* __restrict__ h16) {
    int i = blockIdx.x * 256 + threadIdx.x;
    if (i >= NSCORE) return;
    int b = i >> 19;
    unsigned key = tokey(scores[i]);
    if ((key >> 24) == prefix1[b])
        atomicAdd(&h16[((size_t)b << 16) + ((key >> 8) & 0xFFFFu)], 1u);
}

__global__ __launch_bounds__(256) void scan16_kernel(const unsigned* __restrict__ h16,
                                                     const unsigned* __restrict__ prefix1,
                                                     const unsigned* __restrict__ above1,
                                                     float* __restrict__ Thi,
                                                     float* __restrict__ Tlo) {
    int b = blockIdx.x, tid = threadIdx.x;
    const unsigned* h = h16 + ((size_t)b << 16);
    unsigned k = TOPK_K - above1[b];
    __shared__ unsigned S[256];
    __shared__ int tstar;
    unsigned s = 0;
    const unsigned* seg = h + tid * 256;
    for (int i = 0; i < 256; i++) s += seg[i];
    S[tid] = s;
    __syncthreads();
    for (int off = 1; off < 256; off <<= 1) {
        unsigned a = S[tid];
        unsigned v = (tid + off < 256) ? S[tid + off] : 0u;
        __syncthreads();
        S[tid] = a + v;
        __syncthreads();
    }
    unsigned St = S[tid];
    unsigned Sn = (tid < 255) ? S[tid + 1] : 0u;
    if (St >= k && (tid == 255 || Sn < k)) tstar = tid;
    __syncthreads();
    if (tid == 0) {
        int t = tstar;
        unsigned runn = (t < 255) ? S[t + 1] : 0u;
        unsigned c = (unsigned)t * 256u;
        for (int i = 255; i >= 0; i--) {
            unsigned cc = h[t * 256 + i];
            if (runn + cc >= k) { c = (unsigned)(t * 256 + i); break; }
            runn += cc;
        }
        unsigned P24 = (prefix1[b] << 16) | c;
        float tlo = (P24 < 0x8000u) ? -INFINITY : keytofloat(P24 << 8);
        float thi = (P24 == 0x00FFFFFFu) ? INFINITY
                  : ((P24 + 1u) < 0x8000u ? -INFINITY : keytofloat((P24 + 1u) << 8));
        Thi[b] = thi + MARGIN;
        Tlo[b] = tlo - MARGIN;
    }
}

// ---------------- classify: block-owned tiles, no hot atomics ----------------
__global__ __launch_bounds__(256) void classify_kernel(const float* __restrict__ scores,
                                                       const float* __restrict__ Thi,
                                                       const float* __restrict__ Tlo,
                                                       unsigned* __restrict__ sel,
                                                       unsigned* __restrict__ partialCnt,
                                                       unsigned* __restrict__ bandN,
                                                       unsigned* __restrict__ bandIdx) {
    const int b  = blockIdx.z;
    const int h0 = blockIdx.x * 256;
    const int s0 = blockIdx.y * 16;
    const int c  = threadIdx.x;
    const float thi = Thi[b], tlo = Tlo[b];
    unsigned selbit = 0, cnt = 0;
    const float* base = scores + ((size_t)(b * S_ + s0)) * H_ + h0;
    #pragma unroll 4
    for (int j = 0; j < 16; j++) {
        float sv = base[(size_t)j * H_ + c];
        if (sv > thi) { selbit = 1u; cnt++; }
        else if (sv >= tlo) {
            unsigned slot = atomicAdd(&bandN[b], 1u);
            if (slot < BAND_CAP)
                bandIdx[(b << 13) + slot] = (unsigned)(((s0 + j) << 12) | (h0 + c));
        }
    }
    if (selbit) sel[(b << 12) + h0 + c] = 1u;
    __shared__ unsigned red[256];
    red[c] = cnt;
    __syncthreads();
    for (int off = 128; off; off >>= 1) {
        if (c < off) red[c] += red[c + off];
        __syncthreads();
    }
    if (c == 0) partialCnt[b * 128 + blockIdx.y * 16 + blockIdx.x] = red[0];
}

__global__ void finalize_cnt_kernel(const unsigned* __restrict__ partial,
                                    unsigned* __restrict__ certN) {
    int b = threadIdx.x;
    if (b >= B_) return;
    unsigned s = 0;
    for (int i = 0; i < 128; i++) s += partial[b * 128 + i];
    certN[b] = s;
}

// ---------------- exact fp32 score for band entries ----------------
__global__ __launch_bounds__(256) void band_exact_kernel(const float* __restrict__ g,
                                                         const float* __restrict__ w2,
                                                         const float* __restrict__ b2,
                                                         const unsigned* __restrict__ bandN,
                                                         const unsigned* __restrict__ bandIdx,
                                                         float* __restrict__ bandVal) {
    int wid = (blockIdx.x * 256 + threadIdx.x) >> 6;
    int lane = threadIdx.x & 63;
    for (int b = 0; b < B_; b++) {
        int n = bandN[b]; if (n > BAND_CAP) n = BAND_CAP;
        for (int j = wid; j < n; j += 1024) {
            unsigned f = bandIdx[(b << 13) + j];
            int m = b * S_ + (int)(f >> 12);
            int h = (int)(f & (H_ - 1));
            const float* gr = g  + (size_t)m * H_;
            const float* wr = w2 + (size_t)h * H_;
            float s = 0.0f;
            for (int cc = lane * 4; cc < H_; cc += 256) {
                float4 a = *(const float4*)(gr + cc);
                float4 w = *(const float4*)(wr + cc);
                s += a.x*w.x + a.y*w.y + a.z*w.z + a.w*w.w;
            }
            #pragma unroll
            for (int off = 32; off; off >>= 1) s += __shfl_xor(s, off);
            if (lane == 0) bandVal[(b << 13) + j] = s + b2[h];
        }
    }
}

// ---------------- select top-r of band by (exact desc, flat idx asc) ----------------
__global__ __launch_bounds__(256) void band_select_kernel(const float* __restrict__ bandVal,
                                                          const unsigned* __restrict__ bandIdx,
                                                          const unsigned* __restrict__ bandN,
                                                          const unsigned* __restrict__ certainN,
                                                          unsigned* __restrict__ sel) {
    __shared__ float  sv[BAND_CAP];
    __shared__ unsigned si[BAND_CAP];
    int b = blockIdx.x, tid = threadIdx.x;
    int n = bandN[b]; if (n > BAND_CAP) n = BAND_CAP;
    int r = TOPK_K - (int)certainN[b];
    if (r <= 0) return;
    if (r >= n) {
        for (int j = tid; j < n; j += 256)
            sel[(b << 12) + (bandIdx[(b << 13) + j] & (H_ - 1))] = 1u;
        return;
    }
    for (int j = tid; j < n; j += 256) {
        sv[j] = bandVal[(b << 13) + j];
        si[j] = bandIdx[(b << 13) + j];
    }
    __syncthreads();
    for (int j = tid; j < n; j += 256) {
        float vj = sv[j]; unsigned fj = si[j];
        int rank = 0;
        for (int l = 0; l < n; l++) {
            float vl = sv[l]; unsigned fl = si[l];
            rank += (vl > vj) || (vl == vj && fl < fj);
        }
        if (rank < r) sel[(b << 12) + (fj & (H_ - 1))] = 1u;
    }
}

// ---------------- select + bias + exact GELU -> bf16 ----------------
__global__ __launch_bounds__(256) void act_kernel(const float* __restrict__ hprev,
                                                  const float* __restrict__ hcurr,
                                                  const float* __restrict__ bprev,
                                                  const float* __restrict__ bcurr,
                                                  const unsigned* __restrict__ sel,
                                                  __hip_bfloat16* __restrict__ act) {
    int i = blockIdx.x * 256 + threadIdx.x;
    if (i >= NSCORE) return;
    int h = i & (H_ - 1);
    int b = i >> 19;
    float v = sel[(b << 12) + h] ? (hprev[i] + bprev[h]) : (hcurr[i] + bcurr[h]);
    float gl = 0.5f * v * (1.0f + erff(v * 0.70710678118654752440f));
    act[i] = __float2bfloat16(gl);
}

extern "C" void kernel_launch(void* const* d_in, const int* in_sizes, int n_in,
                              void* d_out, int out_size, void* d_ws, size_t ws_size,
                              hipStream_t stream) {
    const float* x     = (const float*)d_in[0];
    const float* wprev = (const float*)d_in[1];
    const float* bprev = (const float*)d_in[2];
    const float* wcurr = (const float*)d_in[3];
    const float* bcurr = (const float*)d_in[4];
    const float* gw1   = (const float*)d_in[5];
    const float* gb1   = (const float*)d_in[6];
    const float* gw2   = (const float*)d_in[7];
    const float* gb2   = (const float*)d_in[8];
    const float* dw    = (const float*)d_in[9];
    const float* db    = (const float*)d_in[10];
    float* out = (float*)d_out;
    char* ws = (char*)d_ws;

    float* g      = (float*)(ws + G_OFF);
    float* scores = (float*)(ws + SC_OFF);
    float* hprev  = (float*)(ws + G_OFF);
    float* hcurr  = (float*)(ws + SC_OFF);
    float* dpart  = (float*)(ws + GHI_OFF);     // 4 x 4MB after ghi/glo dead
    unsigned short* ghi = (unsigned short*)(ws + GHI_OFF);
    unsigned short* glo = (unsigned short*)(ws + GLO_OFF);
    unsigned short* xhi = (unsigned short*)(ws + XHI_OFF);   // also value-path xb
    unsigned short* xlo = (unsigned short*)(ws + XLO_OFF);
    unsigned short* w1h = (unsigned short*)(ws + W1H_OFF);
    unsigned short* w1l = (unsigned short*)(ws + W1L_OFF);
    unsigned short* w2h = (unsigned short*)(ws + W2H_OFF);
    unsigned short* w2l = (unsigned short*)(ws + W2L_OFF);
    unsigned short* wpb = (unsigned short*)(ws + WPB_OFF);
    unsigned short* wcb = (unsigned short*)(ws + WCB_OFF);
    unsigned short* wdb = (unsigned short*)(ws + WDB_OFF);
    __hip_bfloat16* act = (__hip_bfloat16*)(ws + ACT_OFF);
    unsigned* h8      = (unsigned*)(ws + H8_OFF);
    unsigned* h16     = (unsigned*)(ws + H16_OFF);
    unsigned* sel     = (unsigned*)(ws + SEL_OFF);
    unsigned* certN   = (unsigned*)(ws + CNT_OFF);
    unsigned* bandN   = (unsigned*)(ws + CNT_OFF + 32);
    unsigned* prefix1 = (unsigned*)(ws + CNT_OFF + 64);
    unsigned* above1  = (unsigned*)(ws + CNT_OFF + 96);
    float*    Thi     = (float*)(ws + CNT_OFF + 128);
    float*    Tlo     = (float*)(ws + CNT_OFF + 160);
    unsigned* partCnt = (unsigned*)(ws + PART_OFF);
    unsigned* bandIdx = (unsigned*)(ws + BIDX_OFF);
    float*    bandVal = (float*)(ws + BVAL_OFF);

    hipMemsetAsync(ws + H8_OFF, 0, 65536 + 2097152, stream);      // h8 + pad + h16
    hipMemsetAsync(ws + SEL_OFF, 0, 131072 + 512 + 4096, stream); // sel + counters + partCnt

    // gate path: split inputs, MFMA gemm1 (fused bias+relu+split epi), split w2, MFMA gemm2
    split_kernel<<<(M_*D_/4 + 255)/256, 256, 0, stream>>>(x,   xhi, xlo, M_*D_/4);
    split_kernel<<<(H_*D_/4 + 255)/256, 256, 0, stream>>>(gw1, w1h, w1l, H_*D_/4);
    gemm_split_kernel<1><<<dim3(H_/128, M_/64), 256, 0, stream>>>(
        (const short*)xhi, (const short*)xlo, (const short*)w1h, (const short*)w1l,
        gb1, D_, g, ghi, glo);
    split_kernel<<<(H_*H_/4 + 255)/256, 256, 0, stream>>>(gw2, w2h, w2l, H_*H_/4);
    gemm_split_kernel<0><<<dim3(H_/128, M_/64), 256, 0, stream>>>(
        (const short*)ghi, (const short*)glo, (const short*)w2h, (const short*)w2l,
        gb2, H_, scores, nullptr, nullptr);

    // value-path bf16 weights (overwrite w2h region -> must follow gemm2)
    f2bf3_kernel<<<3*(H_*D_/4)/256, 256, 0, stream>>>(wprev, wcurr, dw, wpb, wcb, wdb);

    // threshold: 8-bit LDS hist -> critical byte -> 16-bit hist -> bin-edge thresholds
    hist8_kernel<<<dim3(64, 8), 256, 0, stream>>>(scores, h8);
    scan8_kernel<<<B_, 256, 0, stream>>>(h8, prefix1, above1);
    hist16_kernel<<<NSCORE/256, 256, 0, stream>>>(scores, prefix1, h16);
    scan16_kernel<<<B_, 256, 0, stream>>>(h16, prefix1, above1, Thi, Tlo);

    // certain marks + band; exact recompute; band top-r
    classify_kernel<<<dim3(16, 8, 8), 256, 0, stream>>>(scores, Thi, Tlo, sel, partCnt, bandN, bandIdx);
    finalize_cnt_kernel<<<1, 64, 0, stream>>>(partCnt, certN);
    band_exact_kernel<<<256, 256, 0, stream>>>(g, gw2, gb2, bandN, bandIdx, bandVal);
    band_select_kernel<<<B_, 256, 0, stream>>>(bandVal, bandIdx, bandN, certN, sel);

    // value path: up (z=2), act, down (split-K=4) + merge
    bgemm_bt_kernel<<<dim3(H_/128, M_/128, 2), 256, 0, stream>>>(
        (const short*)xhi, (const short*)wpb, (const short*)wcb, hprev, hcurr, H_, D_);
    act_kernel<<<NSCORE/256, 256, 0, stream>>>(hprev, hcurr, bprev, bcurr, sel, act);
    bgemm_down_kernel<<<dim3(D_/128, M_/128, 4), 256, 0, stream>>>(
        (const short*)act, (const short*)wdb, dpart);
    down_merge_kernel<<<(M_*D_/4 + 255)/256, 256, 0, stream>>>(dpart, db, out);
}